// Round 4
// baseline (186.655 us; speedup 1.0000x reference)
//
#include <hip/hip_runtime.h>
#include <math.h>

#define N_DIM 1024
#define G_DIM 4096
#define B_DIM 2048
#define K2DIM 2048  // 2*N (real|imag concatenated K)

typedef __attribute__((ext_vector_type(8))) short bf16x8;
typedef __attribute__((ext_vector_type(16))) float f32x16;
typedef unsigned short ushort_t;

// ---------- ws layout (bytes) ----------
#define WS_BRT   0u                      // bf16 [G][2048]  16 MB
#define WS_BIT   (16u << 20)             // bf16 [G][2048]  16 MB
#define WS_HBF   (32u << 20)             // bf16 [B][2048]   8 MB
#define WS_ROWMAX (40u << 20)            // u32 [B]
#define WS_CCNT  (WS_ROWMAX + 8192u)     // int [B]
#define WS_CG    (WS_CCNT + 8192u)       // int [B][64]
#define WS_WG    (WS_CG + 2048u*64u*4u)  // int [B]
#define WS_WXR   (WS_WG + 8192u)         // f32 [B]
#define WS_WXI   (WS_WXR + 8192u)        // f32 [B]

__device__ __forceinline__ unsigned short f2bf(float f) {
  unsigned u = __float_as_uint(f);
  unsigned r = u + 0x7fffu + ((u >> 16) & 1u);
  return (unsigned short)(r >> 16);
}

__device__ __forceinline__ void gload_lds16(const void* gsrc, void* ldst) {
  __builtin_amdgcn_global_load_lds(
      (const __attribute__((address_space(1))) void*)gsrc,
      (__attribute__((address_space(3))) void*)ldst, 16, 0, 0);
}

// ---------- K1: PSI generation (transposed outputs) ----------
__global__ void k_psi(const float* __restrict__ theta, const float* __restrict__ alpha,
                      float* __restrict__ prT, float* __restrict__ piT,
                      ushort_t* __restrict__ brT, ushort_t* __restrict__ biT) {
  __shared__ float sp[32][33], si[32][33];
  const int tx = threadIdx.x, ty = threadIdx.y;
  const int g0 = blockIdx.x * 32, n0 = blockIdx.y * 32;
  for (int rr = ty; rr < 32; rr += 8) {
    const size_t idx = (size_t)(n0 + rr) * G_DIM + g0 + tx;
    float a = tanhf(alpha[idx]) * 0.03125f;  // 1/sqrt(1024)
    float s, c;
    sincosf(theta[idx], &s, &c);
    sp[rr][tx] = a * c;
    si[rr][tx] = a * s;
  }
  __syncthreads();
  for (int rr = ty; rr < 32; rr += 8) {
    const int g = g0 + rr, n = n0 + tx;
    const float pr = sp[tx][rr], pi = si[tx][rr];
    prT[(size_t)g * N_DIM + n] = pr;
    piT[(size_t)g * N_DIM + n] = pi;
    brT[(size_t)g * K2DIM + n] = f2bf(pr);
    brT[(size_t)g * K2DIM + N_DIM + n] = f2bf(-pi);
    biT[(size_t)g * K2DIM + n] = f2bf(pi);
    biT[(size_t)g * K2DIM + N_DIM + n] = f2bf(pr);
  }
}

// ---------- K1b: H -> bf16, layout [B][2048] (Hr | Hi) ----------
__global__ void k_hconv(const float* __restrict__ H, ushort_t* __restrict__ hbf) {
  const int j4 = (blockIdx.x * blockDim.x + threadIdx.x) * 4;
  const int b = j4 >> 11, k = j4 & 2047, c = k >> 10, n = k & 1023;
  const float4 v = *reinterpret_cast<const float4*>(
      H + (size_t)c * (B_DIM * N_DIM) + (size_t)b * N_DIM + n);
  ushort4 u;
  u.x = f2bf(v.x); u.y = f2bf(v.y); u.z = f2bf(v.z); u.w = f2bf(v.w);
  *reinterpret_cast<ushort4*>(hbf + j4) = u;
}

// ---------- K2: 32x32x16 MFMA dual-acc GEMM -> |x|^2 + row max ----------
// BM=256, BN=128, BK=32, 8 waves (2M x 4N), per-wave 128x32 (r+i).
// 4-ring LDS (4 x 32KB: A16|Br8|Bi8), counted vmcnt(8).
__global__ __launch_bounds__(512, 2) void k_gemm(
    const ushort_t* __restrict__ hbf, const ushort_t* __restrict__ brT,
    const ushort_t* __restrict__ biT, float* __restrict__ xabs,
    unsigned* __restrict__ rowmax) {
  __shared__ ushort_t smem[65536];     // 128 KB: 4 bufs x 16384 ushorts
  __shared__ unsigned tilemax[256];
  const int tid = threadIdx.x;
  const int l = tid & 63, w = tid >> 6;
  const int wm = w >> 2, wn = w & 3;
  // XCD mapping: xcd = bid&7 owns g-tiles [4x,4x+3] (B panel 4MB, L2-resident)
  const int bid = blockIdx.x;
  const int xcd = bid & 7, idx = bid >> 3;
  const int g0 = (xcd * 4 + (idx & 3)) * 128;
  const int b0 = (idx >> 2) * 256;

  // 32x32x16 frags: row = l&31, k-group = l>>5. LDS rows 32 ushorts (4x16B slots).
  // Swizzle: slot ^= (row&3) == (l&3) for frag reads (row bases mult of 32).
  int colK[2];
#pragma unroll
  for (int ks = 0; ks < 2; ++ks)
    colK[ks] = (((ks * 2 + (l >> 5)) ^ (l & 3)) * 8);
  int rowA[4], rowB;
#pragma unroll
  for (int mi = 0; mi < 4; ++mi) rowA[mi] = (wm * 128 + mi * 32 + (l & 31)) * 32;
  rowB = (wn * 32 + (l & 31)) * 32;

  // staging: linear LDS dest, inverse-swizzled global source (rule #21)
  const ushort_t* sApt[2];
  int dA[2];
#pragma unroll
  for (int i = 0; i < 2; ++i) {
    const int sl = i * 512 + tid, r = sl >> 2, c = (sl & 3) ^ (r & 3);
    sApt[i] = hbf + (size_t)(b0 + r) * K2DIM + c * 8;
    dA[i] = (i * 512 + (tid & ~63)) * 8;
  }
  const int rB = tid >> 2, cB = (tid & 3) ^ (rB & 3);
  const ushort_t* sBrpt = brT + (size_t)(g0 + rB) * K2DIM + cB * 8;
  const ushort_t* sBipt = biT + (size_t)(g0 + rB) * K2DIM + cB * 8;
  const int dB = (tid & ~63) * 8;

  f32x16 accr[4], acci[4];
#pragma unroll
  for (int mi = 0; mi < 4; ++mi) {
    accr[mi] = (f32x16)(0.f);
    acci[mi] = (f32x16)(0.f);
  }

  // prologue: stage tiles 0,1,2 into bufs 0,1,2
#pragma unroll
  for (int t0 = 0; t0 < 3; ++t0) {
    const int kb = t0 * 32, ob = t0 * 16384;
    gload_lds16(sApt[0] + kb, (void*)(smem + ob + dA[0]));
    gload_lds16(sApt[1] + kb, (void*)(smem + ob + dA[1]));
    gload_lds16(sBrpt + kb, (void*)(smem + ob + 8192 + dB));
    gload_lds16(sBipt + kb, (void*)(smem + ob + 12288 + dB));
  }
  asm volatile("s_waitcnt vmcnt(8)" ::: "memory");  // tile 0 landed
  __syncthreads();

  bf16x8 a[2][2], br[2], bi[2];

  for (int t = 0; t < 64; ++t) {
    const ushort_t* buf = smem + (t & 3) * 16384;
    const ushort_t* bufBr = buf + 8192;
    const ushort_t* bufBi = buf + 12288;

    // ---- P1: read a(mi 0-1), br, bi; issue prefetch t+3; MFMA mi 0-1
#pragma unroll
    for (int mi = 0; mi < 2; ++mi)
#pragma unroll
      for (int ks = 0; ks < 2; ++ks)
        a[mi][ks] = *(const bf16x8*)&buf[rowA[mi] + colK[ks]];
#pragma unroll
    for (int ks = 0; ks < 2; ++ks) {
      br[ks] = *(const bf16x8*)&bufBr[rowB + colK[ks]];
      bi[ks] = *(const bf16x8*)&bufBi[rowB + colK[ks]];
    }
    if (t + 3 < 64) {
      const int kb = (t + 3) * 32, ob = ((t + 3) & 3) * 16384;
      gload_lds16(sApt[0] + kb, (void*)(smem + ob + dA[0]));
      gload_lds16(sApt[1] + kb, (void*)(smem + ob + dA[1]));
      gload_lds16(sBrpt + kb, (void*)(smem + ob + 8192 + dB));
      gload_lds16(sBipt + kb, (void*)(smem + ob + 12288 + dB));
    }
    __builtin_amdgcn_s_barrier();
    asm volatile("s_waitcnt lgkmcnt(0)" ::: "memory");
    __builtin_amdgcn_sched_barrier(0);
    __builtin_amdgcn_s_setprio(1);
#pragma unroll
    for (int mi = 0; mi < 2; ++mi)
#pragma unroll
      for (int ks = 0; ks < 2; ++ks) {
        accr[mi] = __builtin_amdgcn_mfma_f32_32x32x16_bf16(a[mi][ks], br[ks], accr[mi], 0, 0, 0);
        acci[mi] = __builtin_amdgcn_mfma_f32_32x32x16_bf16(a[mi][ks], bi[ks], acci[mi], 0, 0, 0);
      }
    __builtin_amdgcn_s_setprio(0);
    __builtin_amdgcn_s_barrier();

    // ---- P2: read a(mi 2-3); MFMA mi 2-3; counted vmcnt; tile-end barrier
#pragma unroll
    for (int mi = 0; mi < 2; ++mi)
#pragma unroll
      for (int ks = 0; ks < 2; ++ks)
        a[mi][ks] = *(const bf16x8*)&buf[rowA[mi + 2] + colK[ks]];
    __builtin_amdgcn_s_barrier();
    asm volatile("s_waitcnt lgkmcnt(0)" ::: "memory");
    __builtin_amdgcn_sched_barrier(0);
    __builtin_amdgcn_s_setprio(1);
#pragma unroll
    for (int mi = 0; mi < 2; ++mi)
#pragma unroll
      for (int ks = 0; ks < 2; ++ks) {
        accr[mi + 2] = __builtin_amdgcn_mfma_f32_32x32x16_bf16(a[mi][ks], br[ks], accr[mi + 2], 0, 0, 0);
        acci[mi + 2] = __builtin_amdgcn_mfma_f32_32x32x16_bf16(a[mi][ks], bi[ks], acci[mi + 2], 0, 0, 0);
      }
    __builtin_amdgcn_s_setprio(0);
    if (t < 61) {
      asm volatile("s_waitcnt vmcnt(8)" ::: "memory");
    } else if (t == 61) {
      asm volatile("s_waitcnt vmcnt(4)" ::: "memory");
    } else {
      asm volatile("s_waitcnt vmcnt(0)" ::: "memory");
    }
    __builtin_amdgcn_s_barrier();
  }

  // epilogue: |x|^2 + per-row max. C/D: col=l&31, row=(reg&3)+8*(reg>>2)+4*(l>>5)
  if (tid < 256) tilemax[tid] = 0u;
  __syncthreads();
  const int gcol = g0 + wn * 32 + (l & 31);
  const int rbase = wm * 128 + 4 * (l >> 5);
#pragma unroll
  for (int mi = 0; mi < 4; ++mi) {
    const f32x16 r = accr[mi], q = acci[mi];
#pragma unroll
    for (int reg = 0; reg < 16; ++reg) {
      const int row = rbase + mi * 32 + (reg & 3) + 8 * (reg >> 2);
      const float xab = r[reg] * r[reg] + q[reg] * q[reg];
      xabs[(size_t)(b0 + row) * G_DIM + gcol] = xab;
      atomicMax(&tilemax[row], __float_as_uint(xab));
    }
  }
  __syncthreads();
  if (tid < 256) atomicMax(&rowmax[b0 + tid], tilemax[tid]);
}

// ---------- K2b: candidate scan (+ zero-fill the imag x-plane) ----------
__global__ void k_scan(float* __restrict__ xabs, const unsigned* __restrict__ rowmax,
                       int* __restrict__ ccnt, int* __restrict__ cg) {
  const size_t e0 = ((size_t)blockIdx.x * 256 + threadIdx.x) * 4;
  const int b = (int)(e0 >> 12);
  const float thr = __uint_as_float(rowmax[b]) - 0.25f;
  const float4 v = *reinterpret_cast<const float4*>(xabs + e0);
  const int gb = (int)(e0 & 4095);
  if (v.x >= thr) { int p = atomicAdd(&ccnt[b], 1); if (p < 64) cg[b * 64 + p] = gb; }
  if (v.y >= thr) { int p = atomicAdd(&ccnt[b], 1); if (p < 64) cg[b * 64 + p] = gb + 1; }
  if (v.z >= thr) { int p = atomicAdd(&ccnt[b], 1); if (p < 64) cg[b * 64 + p] = gb + 2; }
  if (v.w >= thr) { int p = atomicAdd(&ccnt[b], 1); if (p < 64) cg[b * 64 + p] = gb + 3; }
  *reinterpret_cast<float4*>(xabs + e0) = (float4){0.f, 0.f, 0.f, 0.f};
}

// ---------- K3: fp64 refinement of candidates -> winner ----------
__global__ void k_refine(const float* __restrict__ H, const float* __restrict__ prT,
                         const float* __restrict__ piT, const int* __restrict__ ccnt,
                         const int* __restrict__ cg, int* __restrict__ wg,
                         float* __restrict__ wxr, float* __restrict__ wxi) {
  __shared__ double red[8];
  const int b = blockIdx.x, tid = threadIdx.x;
  const int l = tid & 63, w = tid >> 6;
  int cnt = ccnt[b];
  if (cnt > 64) cnt = 64;
  double best = -1.0, bxr = 0.0, bxi = 0.0;
  int bg = 0;
  for (int ci = 0; ci < cnt; ++ci) {
    const int g = cg[b * 64 + ci];
    double xr = 0.0, xi = 0.0;
    for (int n = tid; n < N_DIM; n += 256) {
      const double hr = H[(size_t)b * N_DIM + n];
      const double hi = H[(size_t)B_DIM * N_DIM + (size_t)b * N_DIM + n];
      const double pr = prT[(size_t)g * N_DIM + n];
      const double pi = piT[(size_t)g * N_DIM + n];
      xr += hr * pr - hi * pi;
      xi += hr * pi + hi * pr;
    }
    for (int off = 32; off; off >>= 1) {
      xr += __shfl_down(xr, off);
      xi += __shfl_down(xi, off);
    }
    if (l == 0) { red[w * 2] = xr; red[w * 2 + 1] = xi; }
    __syncthreads();
    if (tid == 0) {
      const double sxr = red[0] + red[2] + red[4] + red[6];
      const double sxi = red[1] + red[3] + red[5] + red[7];
      const double xab = sxr * sxr + sxi * sxi;
      if (xab > best || (xab == best && g < bg)) { best = xab; bg = g; bxr = sxr; bxi = sxi; }
    }
    __syncthreads();
  }
  if (tid == 0) { wg[b] = bg; wxr[b] = (float)bxr; wxi[b] = (float)bxi; }
}

// ---------- K4: y = winner x conj(PSI column) ----------
__global__ void k_y(const float* __restrict__ prT, const float* __restrict__ piT,
                    const int* __restrict__ wg, const float* __restrict__ wxr,
                    const float* __restrict__ wxi, float* __restrict__ out) {
  const int b = blockIdx.x, tid = threadIdx.x;
  const int g = wg[b];
  const float xr = wxr[b], xi = wxi[b];
  float* yr = out + (size_t)2 * B_DIM * G_DIM + (size_t)b * N_DIM;
  float* yi = yr + (size_t)B_DIM * N_DIM;
  for (int n = tid; n < N_DIM; n += 256) {
    const float pr = prT[(size_t)g * N_DIM + n], pi = piT[(size_t)g * N_DIM + n];
    yr[n] = xr * pr + xi * pi;
    yi[n] = xi * pr - xr * pi;
  }
}

// ---------- K5: scatter winner values into zeroed x ----------
__global__ void k_scatter(const int* __restrict__ wg, const float* __restrict__ wxr,
                          const float* __restrict__ wxi, float* __restrict__ out) {
  const int b = blockIdx.x * 256 + threadIdx.x;
  if (b < B_DIM) {
    const int g = wg[b];
    out[(size_t)b * G_DIM + g] = wxr[b];
    out[(size_t)B_DIM * G_DIM + (size_t)b * G_DIM + g] = wxi[b];
  }
}

extern "C" void kernel_launch(void* const* d_in, const int* in_sizes, int n_in,
                              void* d_out, int out_size, void* d_ws, size_t ws_size,
                              hipStream_t stream) {
  const float* H = (const float*)d_in[0];
  const float* theta = (const float*)d_in[1];
  const float* alpha = (const float*)d_in[2];
  float* out = (float*)d_out;
  char* ws = (char*)d_ws;

  ushort_t* brT = (ushort_t*)(ws + WS_BRT);
  ushort_t* biT = (ushort_t*)(ws + WS_BIT);
  ushort_t* hbf = (ushort_t*)(ws + WS_HBF);
  unsigned* rowmax = (unsigned*)(ws + WS_ROWMAX);
  int* ccnt = (int*)(ws + WS_CCNT);
  int* cg = (int*)(ws + WS_CG);
  int* wg = (int*)(ws + WS_WG);
  float* wxr = (float*)(ws + WS_WXR);
  float* wxi = (float*)(ws + WS_WXI);

  // d_out x-region doubles as scratch until the final memset+scatter:
  float* prT = out;                 // [G][N] f32 (x-real plane)
  float* piT = out + 4194304;       // second half of x-real plane
  float* xabs = out + 8388608;      // [B][G] f32 (x-imag plane)

  hipMemsetAsync(ws + WS_ROWMAX, 0, 16384, stream);  // rowmax + ccnt

  k_psi<<<dim3(G_DIM / 32, N_DIM / 32), dim3(32, 8), 0, stream>>>(theta, alpha, prT, piT, brT, biT);
  k_hconv<<<4096, 256, 0, stream>>>(H, hbf);
  k_gemm<<<256, 512, 0, stream>>>(hbf, brT, biT, xabs, rowmax);
  k_scan<<<8192, 256, 0, stream>>>(xabs, rowmax, ccnt, cg);  // also zeroes imag plane
  k_refine<<<B_DIM, 256, 0, stream>>>(H, prT, piT, ccnt, cg, wg, wxr, wxi);
  k_y<<<B_DIM, 256, 0, stream>>>(prT, piT, wg, wxr, wxi, out);
  hipMemsetAsync(out, 0, (size_t)B_DIM * G_DIM * 4, stream);  // zero real plane (prT/piT scratch)
  k_scatter<<<8, 256, 0, stream>>>(wg, wxr, wxi, out);
}

// Round 5
// 178.073 us; speedup vs baseline: 1.0482x; 1.0482x over previous
//
#include <hip/hip_runtime.h>
#include <math.h>

#define N_DIM 1024
#define G_DIM 4096
#define B_DIM 2048
#define K2DIM 2048  // 2*N (real|imag concatenated K)

typedef __attribute__((ext_vector_type(8))) short bf16x8;
typedef __attribute__((ext_vector_type(16))) float f32x16;
typedef unsigned short ushort_t;

// ---------- ws layout (bytes) ----------
#define WS_BRT   0u                      // bf16 [G][2048]  16 MB
#define WS_BIT   (16u << 20)             // bf16 [G][2048]  16 MB
#define WS_HBF   (32u << 20)             // bf16 [B][2048]   8 MB
#define WS_ROWMAX (40u << 20)            // u32 [B]
#define WS_CCNT  (WS_ROWMAX + 8192u)     // int [B]
#define WS_CG    (WS_CCNT + 8192u)       // int [B][64]
#define WS_WG    (WS_CG + 2048u*64u*4u)  // int [B]
#define WS_WXR   (WS_WG + 8192u)         // f32 [B]
#define WS_WXI   (WS_WXR + 8192u)        // f32 [B]

__device__ __forceinline__ unsigned short f2bf(float f) {
  unsigned u = __float_as_uint(f);
  unsigned r = u + 0x7fffu + ((u >> 16) & 1u);
  return (unsigned short)(r >> 16);
}

__device__ __forceinline__ void gload_lds16(const void* gsrc, void* ldst) {
  __builtin_amdgcn_global_load_lds(
      (const __attribute__((address_space(1))) void*)gsrc,
      (__attribute__((address_space(3))) void*)ldst, 16, 0, 0);
}

// ---------- K1: PSI generation (transposed outputs) ----------
__global__ void k_psi(const float* __restrict__ theta, const float* __restrict__ alpha,
                      float* __restrict__ prT, float* __restrict__ piT,
                      ushort_t* __restrict__ brT, ushort_t* __restrict__ biT) {
  __shared__ float sp[32][33], si[32][33];
  const int tx = threadIdx.x, ty = threadIdx.y;
  const int g0 = blockIdx.x * 32, n0 = blockIdx.y * 32;
  for (int rr = ty; rr < 32; rr += 8) {
    const size_t idx = (size_t)(n0 + rr) * G_DIM + g0 + tx;
    float a = tanhf(alpha[idx]) * 0.03125f;  // 1/sqrt(1024)
    float s, c;
    sincosf(theta[idx], &s, &c);
    sp[rr][tx] = a * c;
    si[rr][tx] = a * s;
  }
  __syncthreads();
  for (int rr = ty; rr < 32; rr += 8) {
    const int g = g0 + rr, n = n0 + tx;
    const float pr = sp[tx][rr], pi = si[tx][rr];
    prT[(size_t)g * N_DIM + n] = pr;
    piT[(size_t)g * N_DIM + n] = pi;
    brT[(size_t)g * K2DIM + n] = f2bf(pr);
    brT[(size_t)g * K2DIM + N_DIM + n] = f2bf(-pi);
    biT[(size_t)g * K2DIM + n] = f2bf(pi);
    biT[(size_t)g * K2DIM + N_DIM + n] = f2bf(pr);
  }
}

// ---------- K1b: H -> bf16, layout [B][2048] (Hr | Hi) ----------
__global__ void k_hconv(const float* __restrict__ H, ushort_t* __restrict__ hbf) {
  const int j4 = (blockIdx.x * blockDim.x + threadIdx.x) * 4;
  const int b = j4 >> 11, k = j4 & 2047, c = k >> 10, n = k & 1023;
  const float4 v = *reinterpret_cast<const float4*>(
      H + (size_t)c * (B_DIM * N_DIM) + (size_t)b * N_DIM + n);
  ushort4 u;
  u.x = f2bf(v.x); u.y = f2bf(v.y); u.z = f2bf(v.z); u.w = f2bf(v.w);
  *reinterpret_cast<ushort4*>(hbf + j4) = u;
}

// ---------- K2: 32x32x16 MFMA dual-acc GEMM -> |x|^2 + row max ----------
// BM=256, BN=128, BK=32, 8 waves (2M x 4N), per-wave 128x32 (r+i).
// 4-ring LDS (4 x 32KB: A16|Br8|Bi8), counted vmcnt(8).
// Swizzle involution for 64-B rows: slot ^= (row>>1)&3  (bank-group = (row&1)*4+slot).
__global__ __launch_bounds__(512, 2) void k_gemm(
    const ushort_t* __restrict__ hbf, const ushort_t* __restrict__ brT,
    const ushort_t* __restrict__ biT, float* __restrict__ xabs,
    unsigned* __restrict__ rowmax) {
  __shared__ ushort_t smem[65536];     // 128 KB: 4 bufs x 16384 ushorts
  __shared__ unsigned tilemax[256];
  const int tid = threadIdx.x;
  const int l = tid & 63, w = tid >> 6;
  const int wm = w >> 2, wn = w & 3;
  // XCD mapping: xcd = bid&7 owns g-tiles [4x,4x+3] (B panel 4MB, L2-resident)
  const int bid = blockIdx.x;
  const int xcd = bid & 7, idx = bid >> 3;
  const int g0 = (xcd * 4 + (idx & 3)) * 128;
  const int b0 = (idx >> 2) * 256;

  // 32x32x16 frags: row = l&31, k-group = l>>5. LDS rows 32 ushorts (4x16B slots).
  // slot ^= (row>>1)&3; for frag rows (bases mult of 32): (row>>1)&3 == (l>>1)&3.
  int colK[2];
#pragma unroll
  for (int ks = 0; ks < 2; ++ks)
    colK[ks] = (((ks * 2 + (l >> 5)) ^ ((l >> 1) & 3)) * 8);
  int rowA[4], rowB;
#pragma unroll
  for (int mi = 0; mi < 4; ++mi) rowA[mi] = (wm * 128 + mi * 32 + (l & 31)) * 32;
  rowB = (wn * 32 + (l & 31)) * 32;

  // staging: linear LDS dest, inverse-swizzled global source (rule #21)
  const ushort_t* sApt[2];
  int dA[2];
#pragma unroll
  for (int i = 0; i < 2; ++i) {
    const int sl = i * 512 + tid, r = sl >> 2, c = (sl & 3) ^ ((r >> 1) & 3);
    sApt[i] = hbf + (size_t)(b0 + r) * K2DIM + c * 8;
    dA[i] = (i * 512 + (tid & ~63)) * 8;
  }
  const int rB = tid >> 2, cB = (tid & 3) ^ ((rB >> 1) & 3);
  const ushort_t* sBrpt = brT + (size_t)(g0 + rB) * K2DIM + cB * 8;
  const ushort_t* sBipt = biT + (size_t)(g0 + rB) * K2DIM + cB * 8;
  const int dB = (tid & ~63) * 8;

  f32x16 accr[4], acci[4];
#pragma unroll
  for (int mi = 0; mi < 4; ++mi) {
    accr[mi] = (f32x16)(0.f);
    acci[mi] = (f32x16)(0.f);
  }

  // prologue: stage tiles 0,1,2 into bufs 0,1,2
#pragma unroll
  for (int t0 = 0; t0 < 3; ++t0) {
    const int kb = t0 * 32, ob = t0 * 16384;
    gload_lds16(sApt[0] + kb, (void*)(smem + ob + dA[0]));
    gload_lds16(sApt[1] + kb, (void*)(smem + ob + dA[1]));
    gload_lds16(sBrpt + kb, (void*)(smem + ob + 8192 + dB));
    gload_lds16(sBipt + kb, (void*)(smem + ob + 12288 + dB));
  }
  asm volatile("s_waitcnt vmcnt(8)" ::: "memory");  // tile 0 landed
  __syncthreads();

  bf16x8 a[2][2], br[2], bi[2];

  for (int t = 0; t < 64; ++t) {
    const ushort_t* buf = smem + (t & 3) * 16384;
    const ushort_t* bufBr = buf + 8192;
    const ushort_t* bufBi = buf + 12288;

    // ---- P1: read a(mi 0-1), br, bi; issue prefetch t+3; MFMA mi 0-1
#pragma unroll
    for (int mi = 0; mi < 2; ++mi)
#pragma unroll
      for (int ks = 0; ks < 2; ++ks)
        a[mi][ks] = *(const bf16x8*)&buf[rowA[mi] + colK[ks]];
#pragma unroll
    for (int ks = 0; ks < 2; ++ks) {
      br[ks] = *(const bf16x8*)&bufBr[rowB + colK[ks]];
      bi[ks] = *(const bf16x8*)&bufBi[rowB + colK[ks]];
    }
    if (t + 3 < 64) {
      const int kb = (t + 3) * 32, ob = ((t + 3) & 3) * 16384;
      gload_lds16(sApt[0] + kb, (void*)(smem + ob + dA[0]));
      gload_lds16(sApt[1] + kb, (void*)(smem + ob + dA[1]));
      gload_lds16(sBrpt + kb, (void*)(smem + ob + 8192 + dB));
      gload_lds16(sBipt + kb, (void*)(smem + ob + 12288 + dB));
    }
    __builtin_amdgcn_s_barrier();
    asm volatile("s_waitcnt lgkmcnt(0)" ::: "memory");
    __builtin_amdgcn_sched_barrier(0);
    __builtin_amdgcn_s_setprio(1);
#pragma unroll
    for (int mi = 0; mi < 2; ++mi)
#pragma unroll
      for (int ks = 0; ks < 2; ++ks) {
        accr[mi] = __builtin_amdgcn_mfma_f32_32x32x16_bf16(a[mi][ks], br[ks], accr[mi], 0, 0, 0);
        acci[mi] = __builtin_amdgcn_mfma_f32_32x32x16_bf16(a[mi][ks], bi[ks], acci[mi], 0, 0, 0);
      }
    __builtin_amdgcn_s_setprio(0);
    __builtin_amdgcn_s_barrier();

    // ---- P2: read a(mi 2-3); MFMA mi 2-3; counted vmcnt; tile-end barrier
#pragma unroll
    for (int mi = 0; mi < 2; ++mi)
#pragma unroll
      for (int ks = 0; ks < 2; ++ks)
        a[mi][ks] = *(const bf16x8*)&buf[rowA[mi + 2] + colK[ks]];
    __builtin_amdgcn_s_barrier();
    asm volatile("s_waitcnt lgkmcnt(0)" ::: "memory");
    __builtin_amdgcn_sched_barrier(0);
    __builtin_amdgcn_s_setprio(1);
#pragma unroll
    for (int mi = 0; mi < 2; ++mi)
#pragma unroll
      for (int ks = 0; ks < 2; ++ks) {
        accr[mi + 2] = __builtin_amdgcn_mfma_f32_32x32x16_bf16(a[mi][ks], br[ks], accr[mi + 2], 0, 0, 0);
        acci[mi + 2] = __builtin_amdgcn_mfma_f32_32x32x16_bf16(a[mi][ks], bi[ks], acci[mi + 2], 0, 0, 0);
      }
    __builtin_amdgcn_s_setprio(0);
    if (t < 61) {
      asm volatile("s_waitcnt vmcnt(8)" ::: "memory");
    } else if (t == 61) {
      asm volatile("s_waitcnt vmcnt(4)" ::: "memory");
    } else {
      asm volatile("s_waitcnt vmcnt(0)" ::: "memory");
    }
    __builtin_amdgcn_s_barrier();
  }

  // epilogue: |x|^2 + per-row max. C/D: col=l&31, row=(reg&3)+8*(reg>>2)+4*(l>>5)
  if (tid < 256) tilemax[tid] = 0u;
  __syncthreads();
  const int gcol = g0 + wn * 32 + (l & 31);
  const int rbase = wm * 128 + 4 * (l >> 5);
#pragma unroll
  for (int mi = 0; mi < 4; ++mi) {
    const f32x16 r = accr[mi], q = acci[mi];
#pragma unroll
    for (int reg = 0; reg < 16; ++reg) {
      const int row = rbase + mi * 32 + (reg & 3) + 8 * (reg >> 2);
      const float xab = r[reg] * r[reg] + q[reg] * q[reg];
      xabs[(size_t)(b0 + row) * G_DIM + gcol] = xab;
      atomicMax(&tilemax[row], __float_as_uint(xab));
    }
  }
  __syncthreads();
  if (tid < 256) atomicMax(&rowmax[b0 + tid], tilemax[tid]);
}

// ---------- K2b: candidate scan (+ zero-fill the imag x-plane) ----------
__global__ void k_scan(float* __restrict__ xabs, const unsigned* __restrict__ rowmax,
                       int* __restrict__ ccnt, int* __restrict__ cg) {
  const size_t e0 = ((size_t)blockIdx.x * 256 + threadIdx.x) * 4;
  const int b = (int)(e0 >> 12);
  const float thr = __uint_as_float(rowmax[b]) - 0.25f;
  const float4 v = *reinterpret_cast<const float4*>(xabs + e0);
  const int gb = (int)(e0 & 4095);
  if (v.x >= thr) { int p = atomicAdd(&ccnt[b], 1); if (p < 64) cg[b * 64 + p] = gb; }
  if (v.y >= thr) { int p = atomicAdd(&ccnt[b], 1); if (p < 64) cg[b * 64 + p] = gb + 1; }
  if (v.z >= thr) { int p = atomicAdd(&ccnt[b], 1); if (p < 64) cg[b * 64 + p] = gb + 2; }
  if (v.w >= thr) { int p = atomicAdd(&ccnt[b], 1); if (p < 64) cg[b * 64 + p] = gb + 3; }
  *reinterpret_cast<float4*>(xabs + e0) = (float4){0.f, 0.f, 0.f, 0.f};
}

// ---------- K3: fp64 refinement of candidates -> winner ----------
__global__ void k_refine(const float* __restrict__ H, const float* __restrict__ prT,
                         const float* __restrict__ piT, const int* __restrict__ ccnt,
                         const int* __restrict__ cg, int* __restrict__ wg,
                         float* __restrict__ wxr, float* __restrict__ wxi) {
  __shared__ double red[8];
  const int b = blockIdx.x, tid = threadIdx.x;
  const int l = tid & 63, w = tid >> 6;
  int cnt = ccnt[b];
  if (cnt > 64) cnt = 64;
  double best = -1.0, bxr = 0.0, bxi = 0.0;
  int bg = 0;
  for (int ci = 0; ci < cnt; ++ci) {
    const int g = cg[b * 64 + ci];
    double xr = 0.0, xi = 0.0;
    for (int n = tid; n < N_DIM; n += 256) {
      const double hr = H[(size_t)b * N_DIM + n];
      const double hi = H[(size_t)B_DIM * N_DIM + (size_t)b * N_DIM + n];
      const double pr = prT[(size_t)g * N_DIM + n];
      const double pi = piT[(size_t)g * N_DIM + n];
      xr += hr * pr - hi * pi;
      xi += hr * pi + hi * pr;
    }
    for (int off = 32; off; off >>= 1) {
      xr += __shfl_down(xr, off);
      xi += __shfl_down(xi, off);
    }
    if (l == 0) { red[w * 2] = xr; red[w * 2 + 1] = xi; }
    __syncthreads();
    if (tid == 0) {
      const double sxr = red[0] + red[2] + red[4] + red[6];
      const double sxi = red[1] + red[3] + red[5] + red[7];
      const double xab = sxr * sxr + sxi * sxi;
      if (xab > best || (xab == best && g < bg)) { best = xab; bg = g; bxr = sxr; bxi = sxi; }
    }
    __syncthreads();
  }
  if (tid == 0) { wg[b] = bg; wxr[b] = (float)bxr; wxi[b] = (float)bxi; }
}

// ---------- K4: y = winner x conj(PSI column) ----------
__global__ void k_y(const float* __restrict__ prT, const float* __restrict__ piT,
                    const int* __restrict__ wg, const float* __restrict__ wxr,
                    const float* __restrict__ wxi, float* __restrict__ out) {
  const int b = blockIdx.x, tid = threadIdx.x;
  const int g = wg[b];
  const float xr = wxr[b], xi = wxi[b];
  float* yr = out + (size_t)2 * B_DIM * G_DIM + (size_t)b * N_DIM;
  float* yi = yr + (size_t)B_DIM * N_DIM;
  for (int n = tid; n < N_DIM; n += 256) {
    const float pr = prT[(size_t)g * N_DIM + n], pi = piT[(size_t)g * N_DIM + n];
    yr[n] = xr * pr + xi * pi;
    yi[n] = xi * pr - xr * pi;
  }
}

// ---------- K5: scatter winner values into zeroed x ----------
__global__ void k_scatter(const int* __restrict__ wg, const float* __restrict__ wxr,
                          const float* __restrict__ wxi, float* __restrict__ out) {
  const int b = blockIdx.x * 256 + threadIdx.x;
  if (b < B_DIM) {
    const int g = wg[b];
    out[(size_t)b * G_DIM + g] = wxr[b];
    out[(size_t)B_DIM * G_DIM + (size_t)b * G_DIM + g] = wxi[b];
  }
}

extern "C" void kernel_launch(void* const* d_in, const int* in_sizes, int n_in,
                              void* d_out, int out_size, void* d_ws, size_t ws_size,
                              hipStream_t stream) {
  const float* H = (const float*)d_in[0];
  const float* theta = (const float*)d_in[1];
  const float* alpha = (const float*)d_in[2];
  float* out = (float*)d_out;
  char* ws = (char*)d_ws;

  ushort_t* brT = (ushort_t*)(ws + WS_BRT);
  ushort_t* biT = (ushort_t*)(ws + WS_BIT);
  ushort_t* hbf = (ushort_t*)(ws + WS_HBF);
  unsigned* rowmax = (unsigned*)(ws + WS_ROWMAX);
  int* ccnt = (int*)(ws + WS_CCNT);
  int* cg = (int*)(ws + WS_CG);
  int* wg = (int*)(ws + WS_WG);
  float* wxr = (float*)(ws + WS_WXR);
  float* wxi = (float*)(ws + WS_WXI);

  // d_out x-region doubles as scratch until the final memset+scatter:
  float* prT = out;                 // [G][N] f32 (x-real plane)
  float* piT = out + 4194304;       // second half of x-real plane
  float* xabs = out + 8388608;      // [B][G] f32 (x-imag plane)

  hipMemsetAsync(ws + WS_ROWMAX, 0, 16384, stream);  // rowmax + ccnt

  k_psi<<<dim3(G_DIM / 32, N_DIM / 32), dim3(32, 8), 0, stream>>>(theta, alpha, prT, piT, brT, biT);
  k_hconv<<<4096, 256, 0, stream>>>(H, hbf);
  k_gemm<<<256, 512, 0, stream>>>(hbf, brT, biT, xabs, rowmax);
  k_scan<<<8192, 256, 0, stream>>>(xabs, rowmax, ccnt, cg);  // also zeroes imag plane
  k_refine<<<B_DIM, 256, 0, stream>>>(H, prT, piT, ccnt, cg, wg, wxr, wxi);
  k_y<<<B_DIM, 256, 0, stream>>>(prT, piT, wg, wxr, wxi, out);
  hipMemsetAsync(out, 0, (size_t)B_DIM * G_DIM * 4, stream);  // zero real plane (prT/piT scratch)
  k_scatter<<<8, 256, 0, stream>>>(wg, wxr, wxi, out);
}

// Round 6
// 150.141 us; speedup vs baseline: 1.2432x; 1.1860x over previous
//
#include <hip/hip_runtime.h>
#include <math.h>

#define N_DIM 1024
#define G_DIM 4096
#define B_DIM 2048
#define K2DIM 2048  // 2*N (real|imag concatenated K)

typedef __attribute__((ext_vector_type(8))) short bf16x8;
typedef __attribute__((ext_vector_type(16))) float f32x16;
typedef unsigned short ushort_t;

// ---------- ws layout (bytes) ----------
#define WS_BRT   0u                      // bf16 [G][2048]  16 MB
#define WS_BIT   (16u << 20)             // bf16 [G][2048]  16 MB
#define WS_HBF   (32u << 20)             // bf16 [B][2048]   8 MB
#define WS_CCNT  (40u << 20)             // int [B]
#define WS_CG    (WS_CCNT + 8192u)       // int [B][64]
#define WS_WG    (WS_CG + 2048u*64u*4u)  // int [B]
#define WS_WXR   (WS_WG + 8192u)         // f32 [B]
#define WS_WXI   (WS_WXR + 8192u)        // f32 [B]

__device__ __forceinline__ unsigned short f2bf(float f) {
  unsigned u = __float_as_uint(f);
  unsigned r = u + 0x7fffu + ((u >> 16) & 1u);
  return (unsigned short)(r >> 16);
}

__device__ __forceinline__ void gload_lds16(const void* gsrc, void* ldst) {
  __builtin_amdgcn_global_load_lds(
      (const __attribute__((address_space(1))) void*)gsrc,
      (__attribute__((address_space(3))) void*)ldst, 16, 0, 0);
}

// ---------- K1: PSI generation (transposed outputs) ----------
__global__ void k_psi(const float* __restrict__ theta, const float* __restrict__ alpha,
                      float* __restrict__ prT, float* __restrict__ piT,
                      ushort_t* __restrict__ brT, ushort_t* __restrict__ biT) {
  __shared__ float sp[32][33], si[32][33];
  const int tx = threadIdx.x, ty = threadIdx.y;
  const int g0 = blockIdx.x * 32, n0 = blockIdx.y * 32;
  for (int rr = ty; rr < 32; rr += 8) {
    const size_t idx = (size_t)(n0 + rr) * G_DIM + g0 + tx;
    float a = tanhf(alpha[idx]) * 0.03125f;  // 1/sqrt(1024)
    float s, c;
    sincosf(theta[idx], &s, &c);
    sp[rr][tx] = a * c;
    si[rr][tx] = a * s;
  }
  __syncthreads();
  for (int rr = ty; rr < 32; rr += 8) {
    const int g = g0 + rr, n = n0 + tx;
    const float pr = sp[tx][rr], pi = si[tx][rr];
    prT[(size_t)g * N_DIM + n] = pr;
    piT[(size_t)g * N_DIM + n] = pi;
    brT[(size_t)g * K2DIM + n] = f2bf(pr);
    brT[(size_t)g * K2DIM + N_DIM + n] = f2bf(-pi);
    biT[(size_t)g * K2DIM + n] = f2bf(pi);
    biT[(size_t)g * K2DIM + N_DIM + n] = f2bf(pr);
  }
}

// ---------- K1b: H -> bf16, layout [B][2048] (Hr | Hi) ----------
__global__ void k_hconv(const float* __restrict__ H, ushort_t* __restrict__ hbf) {
  const int j4 = (blockIdx.x * blockDim.x + threadIdx.x) * 4;
  const int b = j4 >> 11, k = j4 & 2047, c = k >> 10, n = k & 1023;
  const float4 v = *reinterpret_cast<const float4*>(
      H + (size_t)c * (B_DIM * N_DIM) + (size_t)b * N_DIM + n);
  ushort4 u;
  u.x = f2bf(v.x); u.y = f2bf(v.y); u.z = f2bf(v.z); u.w = f2bf(v.w);
  *reinterpret_cast<ushort4*>(hbf + j4) = u;
}

// ---------- K2: 32x32x16 MFMA dual-acc GEMM -> |x|^2 ----------
// BM=256, BN=128, BK=64, 8 waves (2M x 4N), per-wave 128x32 (r+i).
// LDS: 2-ring x 64KB (A32|Br16|Bi16), 128-B rows, full 3-bit swizzle slot^=row&7.
__global__ __launch_bounds__(512, 2) void k_gemm(
    const ushort_t* __restrict__ hbf, const ushort_t* __restrict__ brT,
    const ushort_t* __restrict__ biT, float* __restrict__ xabs) {
  __shared__ ushort_t smem[65536];     // 128 KB: 2 bufs x 32768 ushorts
  const int tid = threadIdx.x;
  const int l = tid & 63, w = tid >> 6;
  const int wm = w >> 2, wn = w & 3;
  // XCD mapping: xcd = bid&7 owns g-tiles [4x,4x+3] (B panel 4MB, L2-resident)
  const int bid = blockIdx.x;
  const int xcd = bid & 7, idx = bid >> 3;
  const int g0 = (xcd * 4 + (idx & 3)) * 128;
  const int b0 = (idx >> 2) * 256;

  // 32x32x16 frags: row = l&31, k-half = l>>5. Rows 64 ushorts (8 x 16B slots).
  // Swizzle slot ^= row&7; frag rows (bases mult of 32): row&7 == l&7.
  int colK[4];
#pragma unroll
  for (int ks = 0; ks < 4; ++ks)
    colK[ks] = (((ks * 2 + (l >> 5)) ^ (l & 7)) * 8);
  int rowA[4], rowB;
#pragma unroll
  for (int mi = 0; mi < 4; ++mi) rowA[mi] = (wm * 128 + mi * 32 + (l & 31)) * 64;
  rowB = (wn * 32 + (l & 31)) * 64;

  // staging: linear LDS dest (gload_lds), inverse-swizzled global source (rule #21)
  const ushort_t* sApt[4];
  int dA[4];
#pragma unroll
  for (int i = 0; i < 4; ++i) {
    const int sl = i * 512 + tid, r = sl >> 3, c = (sl & 7) ^ (r & 7);
    sApt[i] = hbf + (size_t)(b0 + r) * K2DIM + c * 8;
    dA[i] = (i * 512 + (tid & ~63)) * 8;
  }
  const ushort_t* sBrpt[2];
  const ushort_t* sBipt[2];
  int dB[2];
#pragma unroll
  for (int i = 0; i < 2; ++i) {
    const int sl = i * 512 + tid, r = sl >> 3, c = (sl & 7) ^ (r & 7);
    sBrpt[i] = brT + (size_t)(g0 + r) * K2DIM + c * 8;
    sBipt[i] = biT + (size_t)(g0 + r) * K2DIM + c * 8;
    dB[i] = (i * 512 + (tid & ~63)) * 8;
  }

  f32x16 accr[4], acci[4];
#pragma unroll
  for (int mi = 0; mi < 4; ++mi) {
    accr[mi] = (f32x16)(0.f);
    acci[mi] = (f32x16)(0.f);
  }

  // prologue: stage tile 0 into buf 0
#pragma unroll
  for (int i = 0; i < 4; ++i) gload_lds16(sApt[i], (void*)(smem + dA[i]));
#pragma unroll
  for (int i = 0; i < 2; ++i) {
    gload_lds16(sBrpt[i], (void*)(smem + 16384 + dB[i]));
    gload_lds16(sBipt[i], (void*)(smem + 24576 + dB[i]));
  }
  asm volatile("s_waitcnt vmcnt(0)" ::: "memory");
  __syncthreads();

  bf16x8 a1[2][4], a2[2][4], br[4], bi[4];

  for (int t = 0; t < 32; ++t) {
    const ushort_t* buf = smem + (t & 1) * 32768;
    const ushort_t* bufBr = buf + 16384;
    const ushort_t* bufBi = buf + 24576;
    const int nb = ((t + 1) & 1) * 32768;
    const int kp = (t + 1) * 64;
    const bool pf = (t < 31);

    // ---- P1: read a(mi 0-1), br, bi; issue A prefetch; MFMA mi 0-1
#pragma unroll
    for (int mi = 0; mi < 2; ++mi)
#pragma unroll
      for (int ks = 0; ks < 4; ++ks)
        a1[mi][ks] = *(const bf16x8*)&buf[rowA[mi] + colK[ks]];
#pragma unroll
    for (int ks = 0; ks < 4; ++ks) {
      br[ks] = *(const bf16x8*)&bufBr[rowB + colK[ks]];
      bi[ks] = *(const bf16x8*)&bufBi[rowB + colK[ks]];
    }
    if (pf) {
#pragma unroll
      for (int i = 0; i < 4; ++i)
        gload_lds16(sApt[i] + kp, (void*)(smem + nb + dA[i]));
    }
    __builtin_amdgcn_s_barrier();
    asm volatile("s_waitcnt lgkmcnt(0)" ::: "memory");
    __builtin_amdgcn_sched_barrier(0);
    __builtin_amdgcn_s_setprio(1);
#pragma unroll
    for (int mi = 0; mi < 2; ++mi)
#pragma unroll
      for (int ks = 0; ks < 4; ++ks) {
        accr[mi] = __builtin_amdgcn_mfma_f32_32x32x16_bf16(a1[mi][ks], br[ks], accr[mi], 0, 0, 0);
        acci[mi] = __builtin_amdgcn_mfma_f32_32x32x16_bf16(a1[mi][ks], bi[ks], acci[mi], 0, 0, 0);
      }
    __builtin_amdgcn_s_setprio(0);
    __builtin_amdgcn_s_barrier();

    // ---- P2: read a(mi 2-3); issue B prefetch; MFMA mi 2-3; tile-end drain
#pragma unroll
    for (int mi = 0; mi < 2; ++mi)
#pragma unroll
      for (int ks = 0; ks < 4; ++ks)
        a2[mi][ks] = *(const bf16x8*)&buf[rowA[mi + 2] + colK[ks]];
    if (pf) {
#pragma unroll
      for (int i = 0; i < 2; ++i) {
        gload_lds16(sBrpt[i] + kp, (void*)(smem + nb + 16384 + dB[i]));
        gload_lds16(sBipt[i] + kp, (void*)(smem + nb + 24576 + dB[i]));
      }
    }
    __builtin_amdgcn_s_barrier();
    asm volatile("s_waitcnt lgkmcnt(0)" ::: "memory");
    __builtin_amdgcn_sched_barrier(0);
    __builtin_amdgcn_s_setprio(1);
#pragma unroll
    for (int mi = 0; mi < 2; ++mi)
#pragma unroll
      for (int ks = 0; ks < 4; ++ks) {
        accr[mi + 2] = __builtin_amdgcn_mfma_f32_32x32x16_bf16(a2[mi][ks], br[ks], accr[mi + 2], 0, 0, 0);
        acci[mi + 2] = __builtin_amdgcn_mfma_f32_32x32x16_bf16(a2[mi][ks], bi[ks], acci[mi + 2], 0, 0, 0);
      }
    __builtin_amdgcn_s_setprio(0);
    asm volatile("s_waitcnt vmcnt(0)" ::: "memory");
    __syncthreads();
  }

  // epilogue: |x|^2 only. C/D: col=l&31, row=(reg&3)+8*(reg>>2)+4*(l>>5)
  const int gcol = g0 + wn * 32 + (l & 31);
  const int rbase = wm * 128 + 4 * (l >> 5);
#pragma unroll
  for (int mi = 0; mi < 4; ++mi) {
    const f32x16 r = accr[mi], q = acci[mi];
#pragma unroll
    for (int reg = 0; reg < 16; ++reg) {
      const int row = rbase + mi * 32 + (reg & 3) + 8 * (reg >> 2);
      xabs[(size_t)(b0 + row) * G_DIM + gcol] = r[reg] * r[reg] + q[reg] * q[reg];
    }
  }
}

// ---------- K2b: per-row max + candidate scan + zero-fill (block per row) ----
__global__ __launch_bounds__(256) void k_scan(float* __restrict__ xabs,
                                              int* __restrict__ ccnt,
                                              int* __restrict__ cg) {
  __shared__ float red[4];
  const int b = blockIdx.x, tid = threadIdx.x;
  const int l = tid & 63, w = tid >> 6;
  float4 v[4];
  float m = -1.f;
#pragma unroll
  for (int j = 0; j < 4; ++j) {
    v[j] = *reinterpret_cast<const float4*>(xabs + (size_t)b * G_DIM + j * 1024 + tid * 4);
    m = fmaxf(m, fmaxf(fmaxf(v[j].x, v[j].y), fmaxf(v[j].z, v[j].w)));
  }
#pragma unroll
  for (int off = 32; off; off >>= 1) m = fmaxf(m, __shfl_xor(m, off));
  if (l == 0) red[w] = m;
  __syncthreads();
  const float thr = fmaxf(fmaxf(red[0], red[1]), fmaxf(red[2], red[3])) - 0.25f;
#pragma unroll
  for (int j = 0; j < 4; ++j) {
    const int gb = j * 1024 + tid * 4;
    if (v[j].x >= thr) { int p = atomicAdd(&ccnt[b], 1); if (p < 64) cg[b * 64 + p] = gb; }
    if (v[j].y >= thr) { int p = atomicAdd(&ccnt[b], 1); if (p < 64) cg[b * 64 + p] = gb + 1; }
    if (v[j].z >= thr) { int p = atomicAdd(&ccnt[b], 1); if (p < 64) cg[b * 64 + p] = gb + 2; }
    if (v[j].w >= thr) { int p = atomicAdd(&ccnt[b], 1); if (p < 64) cg[b * 64 + p] = gb + 3; }
    *reinterpret_cast<float4*>(xabs + (size_t)b * G_DIM + gb) = (float4){0.f, 0.f, 0.f, 0.f};
  }
}

// ---------- K3: fp64 refinement of candidates -> winner ----------
__global__ void k_refine(const float* __restrict__ H, const float* __restrict__ prT,
                         const float* __restrict__ piT, const int* __restrict__ ccnt,
                         const int* __restrict__ cg, int* __restrict__ wg,
                         float* __restrict__ wxr, float* __restrict__ wxi) {
  __shared__ double red[8];
  const int b = blockIdx.x, tid = threadIdx.x;
  const int l = tid & 63, w = tid >> 6;
  int cnt = ccnt[b];
  if (cnt > 64) cnt = 64;
  double best = -1.0, bxr = 0.0, bxi = 0.0;
  int bg = 0;
  for (int ci = 0; ci < cnt; ++ci) {
    const int g = cg[b * 64 + ci];
    double xr = 0.0, xi = 0.0;
    for (int n = tid; n < N_DIM; n += 256) {
      const double hr = H[(size_t)b * N_DIM + n];
      const double hi = H[(size_t)B_DIM * N_DIM + (size_t)b * N_DIM + n];
      const double pr = prT[(size_t)g * N_DIM + n];
      const double pi = piT[(size_t)g * N_DIM + n];
      xr += hr * pr - hi * pi;
      xi += hr * pi + hi * pr;
    }
    for (int off = 32; off; off >>= 1) {
      xr += __shfl_down(xr, off);
      xi += __shfl_down(xi, off);
    }
    if (l == 0) { red[w * 2] = xr; red[w * 2 + 1] = xi; }
    __syncthreads();
    if (tid == 0) {
      const double sxr = red[0] + red[2] + red[4] + red[6];
      const double sxi = red[1] + red[3] + red[5] + red[7];
      const double xab = sxr * sxr + sxi * sxi;
      if (xab > best || (xab == best && g < bg)) { best = xab; bg = g; bxr = sxr; bxi = sxi; }
    }
    __syncthreads();
  }
  if (tid == 0) { wg[b] = bg; wxr[b] = (float)bxr; wxi[b] = (float)bxi; }
}

// ---------- K4: y = winner x conj(PSI column) ----------
__global__ void k_y(const float* __restrict__ prT, const float* __restrict__ piT,
                    const int* __restrict__ wg, const float* __restrict__ wxr,
                    const float* __restrict__ wxi, float* __restrict__ out) {
  const int b = blockIdx.x, tid = threadIdx.x;
  const int g = wg[b];
  const float xr = wxr[b], xi = wxi[b];
  float* yr = out + (size_t)2 * B_DIM * G_DIM + (size_t)b * N_DIM;
  float* yi = yr + (size_t)B_DIM * N_DIM;
  for (int n = tid; n < N_DIM; n += 256) {
    const float pr = prT[(size_t)g * N_DIM + n], pi = piT[(size_t)g * N_DIM + n];
    yr[n] = xr * pr + xi * pi;
    yi[n] = xi * pr - xr * pi;
  }
}

// ---------- K5: scatter winner values into zeroed x ----------
__global__ void k_scatter(const int* __restrict__ wg, const float* __restrict__ wxr,
                          const float* __restrict__ wxi, float* __restrict__ out) {
  const int b = blockIdx.x * 256 + threadIdx.x;
  if (b < B_DIM) {
    const int g = wg[b];
    out[(size_t)b * G_DIM + g] = wxr[b];
    out[(size_t)B_DIM * G_DIM + (size_t)b * G_DIM + g] = wxi[b];
  }
}

extern "C" void kernel_launch(void* const* d_in, const int* in_sizes, int n_in,
                              void* d_out, int out_size, void* d_ws, size_t ws_size,
                              hipStream_t stream) {
  const float* H = (const float*)d_in[0];
  const float* theta = (const float*)d_in[1];
  const float* alpha = (const float*)d_in[2];
  float* out = (float*)d_out;
  char* ws = (char*)d_ws;

  ushort_t* brT = (ushort_t*)(ws + WS_BRT);
  ushort_t* biT = (ushort_t*)(ws + WS_BIT);
  ushort_t* hbf = (ushort_t*)(ws + WS_HBF);
  int* ccnt = (int*)(ws + WS_CCNT);
  int* cg = (int*)(ws + WS_CG);
  int* wg = (int*)(ws + WS_WG);
  float* wxr = (float*)(ws + WS_WXR);
  float* wxi = (float*)(ws + WS_WXI);

  // d_out x-region doubles as scratch until the final memset+scatter:
  float* prT = out;                 // [G][N] f32 (x-real plane)
  float* piT = out + 4194304;       // second half of x-real plane
  float* xabs = out + 8388608;      // [B][G] f32 (x-imag plane)

  hipMemsetAsync(ws + WS_CCNT, 0, 8192, stream);  // ccnt

  k_psi<<<dim3(G_DIM / 32, N_DIM / 32), dim3(32, 8), 0, stream>>>(theta, alpha, prT, piT, brT, biT);
  k_hconv<<<4096, 256, 0, stream>>>(H, hbf);
  k_gemm<<<256, 512, 0, stream>>>(hbf, brT, biT, xabs);
  k_scan<<<B_DIM, 256, 0, stream>>>(xabs, ccnt, cg);  // row max + scan + zero imag plane
  k_refine<<<B_DIM, 256, 0, stream>>>(H, prT, piT, ccnt, cg, wg, wxr, wxi);
  k_y<<<B_DIM, 256, 0, stream>>>(prT, piT, wg, wxr, wxi, out);
  hipMemsetAsync(out, 0, (size_t)B_DIM * G_DIM * 4, stream);  // zero real plane (prT/piT scratch)
  k_scatter<<<8, 256, 0, stream>>>(wg, wxr, wxi, out);
}

// Round 7
// 145.224 us; speedup vs baseline: 1.2853x; 1.0339x over previous
//
#include <hip/hip_runtime.h>
#include <math.h>

#define N_DIM 1024
#define G_DIM 4096
#define B_DIM 2048
#define K2DIM 2048  // 2*N (real|imag concatenated K)

typedef __attribute__((ext_vector_type(8))) short bf16x8;
typedef __attribute__((ext_vector_type(16))) float f32x16;
typedef unsigned short ushort_t;

// ---------- ws layout (bytes) ----------
#define WS_BRT   0u                      // bf16 [G][2048]  16 MB
#define WS_BIT   (16u << 20)             // bf16 [G][2048]  16 MB
#define WS_HBF   (32u << 20)             // bf16 [B][2048]   8 MB
#define WS_CCNT  (40u << 20)             // int [B]
#define WS_CG    (WS_CCNT + 8192u)       // int [B][64]
#define WS_WG    (WS_CG + 2048u*64u*4u)  // int [B]
#define WS_WXR   (WS_WG + 8192u)         // f32 [B]
#define WS_WXI   (WS_WXR + 8192u)        // f32 [B]

__device__ __forceinline__ unsigned short f2bf(float f) {
  unsigned u = __float_as_uint(f);
  unsigned r = u + 0x7fffu + ((u >> 16) & 1u);
  return (unsigned short)(r >> 16);
}

__device__ __forceinline__ void gload_lds16(const void* gsrc, void* ldst) {
  __builtin_amdgcn_global_load_lds(
      (const __attribute__((address_space(1))) void*)gsrc,
      (__attribute__((address_space(3))) void*)ldst, 16, 0, 0);
}

// ---------- K1: PSI generation (transposed outputs) ----------
__global__ void k_psi(const float* __restrict__ theta, const float* __restrict__ alpha,
                      float* __restrict__ prT, float* __restrict__ piT,
                      ushort_t* __restrict__ brT, ushort_t* __restrict__ biT) {
  __shared__ float sp[32][33], si[32][33];
  const int tx = threadIdx.x, ty = threadIdx.y;
  const int g0 = blockIdx.x * 32, n0 = blockIdx.y * 32;
  for (int rr = ty; rr < 32; rr += 8) {
    const size_t idx = (size_t)(n0 + rr) * G_DIM + g0 + tx;
    float a = tanhf(alpha[idx]) * 0.03125f;  // 1/sqrt(1024)
    float s, c;
    sincosf(theta[idx], &s, &c);
    sp[rr][tx] = a * c;
    si[rr][tx] = a * s;
  }
  __syncthreads();
  for (int rr = ty; rr < 32; rr += 8) {
    const int g = g0 + rr, n = n0 + tx;
    const float pr = sp[tx][rr], pi = si[tx][rr];
    prT[(size_t)g * N_DIM + n] = pr;
    piT[(size_t)g * N_DIM + n] = pi;
    brT[(size_t)g * K2DIM + n] = f2bf(pr);
    brT[(size_t)g * K2DIM + N_DIM + n] = f2bf(-pi);
    biT[(size_t)g * K2DIM + n] = f2bf(pi);
    biT[(size_t)g * K2DIM + N_DIM + n] = f2bf(pr);
  }
}

// ---------- K1b: H -> bf16, layout [B][2048] (Hr | Hi) ----------
__global__ void k_hconv(const float* __restrict__ H, ushort_t* __restrict__ hbf) {
  const int j4 = (blockIdx.x * blockDim.x + threadIdx.x) * 4;
  const int b = j4 >> 11, k = j4 & 2047, c = k >> 10, n = k & 1023;
  const float4 v = *reinterpret_cast<const float4*>(
      H + (size_t)c * (B_DIM * N_DIM) + (size_t)b * N_DIM + n);
  ushort4 u;
  u.x = f2bf(v.x); u.y = f2bf(v.y); u.z = f2bf(v.z); u.w = f2bf(v.w);
  *reinterpret_cast<ushort4*>(hbf + j4) = u;
}

#define LGKM(n) asm volatile("s_waitcnt lgkmcnt(" #n ")" ::: "memory")
#define SB0() __builtin_amdgcn_sched_barrier(0)

// ---------- K2: 32x32x16 MFMA dual-acc GEMM -> |x|^2 ----------
// BM=256, BN=128, BK=64, 8 waves (2M x 4N). LDS 2-ring x 64KB, slot^=row&7.
// Register-pipelined sub-phases: phase p MFMAs subtile p while reading p+1
// (counted lgkmcnt); ONE barrier per K-tile.
__global__ __launch_bounds__(512, 2) void k_gemm(
    const ushort_t* __restrict__ hbf, const ushort_t* __restrict__ brT,
    const ushort_t* __restrict__ biT, float* __restrict__ xabs) {
  __shared__ ushort_t smem[65536];     // 128 KB: 2 bufs x 32768 ushorts
  const int tid = threadIdx.x;
  const int l = tid & 63, w = tid >> 6;
  const int wm = w >> 2, wn = w & 3;
  // XCD mapping: xcd = bid&7 owns g-tiles [4x,4x+3] (B panel 4MB, L2-resident)
  const int bid = blockIdx.x;
  const int xcd = bid & 7, idx = bid >> 3;
  const int g0 = (xcd * 4 + (idx & 3)) * 128;
  const int b0 = (idx >> 2) * 256;

  // 32x32x16 frags: row = l&31, k-half = l>>5. Rows 64 ushorts (8 x 16B slots).
  // Swizzle slot ^= row&7; frag rows (bases mult of 32): row&7 == l&7.
  int colK[4];
#pragma unroll
  for (int ks = 0; ks < 4; ++ks)
    colK[ks] = (((ks * 2 + (l >> 5)) ^ (l & 7)) * 8);
  int rowA[4], rowB;
#pragma unroll
  for (int mi = 0; mi < 4; ++mi) rowA[mi] = (wm * 128 + mi * 32 + (l & 31)) * 64;
  rowB = (wn * 32 + (l & 31)) * 64;

  // staging: linear LDS dest (gload_lds), inverse-swizzled global source (#21)
  const int rS = tid >> 3, cS = (tid & 7) ^ ((tid >> 3) & 7);
  const ushort_t* sA0 = hbf + (size_t)(b0 + rS) * K2DIM + cS * 8;
  const ushort_t* sBr0 = brT + (size_t)(g0 + rS) * K2DIM + cS * 8;
  const ushort_t* sBi0 = biT + (size_t)(g0 + rS) * K2DIM + cS * 8;
  const int dS = (tid & ~63) * 8;  // + i*4096 per 64-row group

  f32x16 accr[4], acci[4];
#pragma unroll
  for (int mi = 0; mi < 4; ++mi) {
    accr[mi] = (f32x16)(0.f);
    acci[mi] = (f32x16)(0.f);
  }

  // prologue: stage tile 0 into buf 0
#pragma unroll
  for (int i = 0; i < 4; ++i)
    gload_lds16(sA0 + i * (64 * K2DIM), (void*)(smem + dS + i * 4096));
#pragma unroll
  for (int i = 0; i < 2; ++i) {
    gload_lds16(sBr0 + i * (64 * K2DIM), (void*)(smem + 16384 + dS + i * 4096));
    gload_lds16(sBi0 + i * (64 * K2DIM), (void*)(smem + 24576 + dS + i * 4096));
  }
  asm volatile("s_waitcnt vmcnt(0)" ::: "memory");
  __builtin_amdgcn_s_barrier();

  bf16x8 aA[2][2], aB[2][2], brL[2], brH[2], biL[2], biH[2];

  // pre-read S0 of tile 0 (8 ds_reads outstanding entering the loop)
  {
    const ushort_t* buf = smem;
#pragma unroll
    for (int mi = 0; mi < 2; ++mi)
#pragma unroll
      for (int k = 0; k < 2; ++k)
        aA[mi][k] = *(const bf16x8*)&buf[rowA[mi] + colK[k]];
#pragma unroll
    for (int k = 0; k < 2; ++k) {
      brL[k] = *(const bf16x8*)&buf[16384 + rowB + colK[k]];
      biL[k] = *(const bf16x8*)&buf[24576 + rowB + colK[k]];
    }
  }

  for (int t = 0; t < 32; ++t) {
    const ushort_t* buf = smem + (t & 1) * 32768;
    const int nb = ((t + 1) & 1) * 32768;
    const int kp = (t + 1) * 64;
    const bool pf = (t < 31);

    // ---- P0: issue S1 reads (aB,brH,biH) + A-stage; MFMA S0
#pragma unroll
    for (int mi = 0; mi < 2; ++mi)
#pragma unroll
      for (int k = 0; k < 2; ++k)
        aB[mi][k] = *(const bf16x8*)&buf[rowA[mi] + colK[k + 2]];
#pragma unroll
    for (int k = 0; k < 2; ++k) {
      brH[k] = *(const bf16x8*)&buf[16384 + rowB + colK[k + 2]];
      biH[k] = *(const bf16x8*)&buf[24576 + rowB + colK[k + 2]];
    }
    if (pf) {
#pragma unroll
      for (int i = 0; i < 4; ++i)
        gload_lds16(sA0 + i * (64 * K2DIM) + kp, (void*)(smem + nb + dS + i * 4096));
    }
    LGKM(8); SB0();
    __builtin_amdgcn_s_setprio(1);
#pragma unroll
    for (int mi = 0; mi < 2; ++mi)
#pragma unroll
      for (int k = 0; k < 2; ++k) {
        accr[mi] = __builtin_amdgcn_mfma_f32_32x32x16_bf16(aA[mi][k], brL[k], accr[mi], 0, 0, 0);
        acci[mi] = __builtin_amdgcn_mfma_f32_32x32x16_bf16(aA[mi][k], biL[k], acci[mi], 0, 0, 0);
      }
    __builtin_amdgcn_s_setprio(0);

    // ---- P1: issue S2 reads (aA = a23,kLo) + B-stage; MFMA S1
#pragma unroll
    for (int mi = 0; mi < 2; ++mi)
#pragma unroll
      for (int k = 0; k < 2; ++k)
        aA[mi][k] = *(const bf16x8*)&buf[rowA[mi + 2] + colK[k]];
    if (pf) {
#pragma unroll
      for (int i = 0; i < 2; ++i) {
        gload_lds16(sBr0 + i * (64 * K2DIM) + kp, (void*)(smem + nb + 16384 + dS + i * 4096));
        gload_lds16(sBi0 + i * (64 * K2DIM) + kp, (void*)(smem + nb + 24576 + dS + i * 4096));
      }
    }
    LGKM(4); SB0();
    __builtin_amdgcn_s_setprio(1);
#pragma unroll
    for (int mi = 0; mi < 2; ++mi)
#pragma unroll
      for (int k = 0; k < 2; ++k) {
        accr[mi] = __builtin_amdgcn_mfma_f32_32x32x16_bf16(aB[mi][k], brH[k], accr[mi], 0, 0, 0);
        acci[mi] = __builtin_amdgcn_mfma_f32_32x32x16_bf16(aB[mi][k], biH[k], acci[mi], 0, 0, 0);
      }
    __builtin_amdgcn_s_setprio(0);

    // ---- P2: issue S3 reads (aB = a23,kHi); MFMA S2
#pragma unroll
    for (int mi = 0; mi < 2; ++mi)
#pragma unroll
      for (int k = 0; k < 2; ++k)
        aB[mi][k] = *(const bf16x8*)&buf[rowA[mi + 2] + colK[k + 2]];
    LGKM(4); SB0();
    __builtin_amdgcn_s_setprio(1);
#pragma unroll
    for (int mi = 0; mi < 2; ++mi)
#pragma unroll
      for (int k = 0; k < 2; ++k) {
        accr[mi + 2] = __builtin_amdgcn_mfma_f32_32x32x16_bf16(aA[mi][k], brL[k], accr[mi + 2], 0, 0, 0);
        acci[mi + 2] = __builtin_amdgcn_mfma_f32_32x32x16_bf16(aA[mi][k], biL[k], acci[mi + 2], 0, 0, 0);
      }
    __builtin_amdgcn_s_setprio(0);

    // ---- P3: tile boundary (vmcnt+barrier), issue next-tile S0; MFMA S3
    LGKM(0); SB0();
    if (pf) {
      asm volatile("s_waitcnt vmcnt(0)" ::: "memory");
      __builtin_amdgcn_s_barrier();
      const ushort_t* bn = smem + nb;
#pragma unroll
      for (int mi = 0; mi < 2; ++mi)
#pragma unroll
        for (int k = 0; k < 2; ++k)
          aA[mi][k] = *(const bf16x8*)&bn[rowA[mi] + colK[k]];
#pragma unroll
      for (int k = 0; k < 2; ++k) {
        brL[k] = *(const bf16x8*)&bn[16384 + rowB + colK[k]];
        biL[k] = *(const bf16x8*)&bn[24576 + rowB + colK[k]];
      }
      SB0();
    }
    __builtin_amdgcn_s_setprio(1);
#pragma unroll
    for (int mi = 0; mi < 2; ++mi)
#pragma unroll
      for (int k = 0; k < 2; ++k) {
        accr[mi + 2] = __builtin_amdgcn_mfma_f32_32x32x16_bf16(aB[mi][k], brH[k], accr[mi + 2], 0, 0, 0);
        acci[mi + 2] = __builtin_amdgcn_mfma_f32_32x32x16_bf16(aB[mi][k], biH[k], acci[mi + 2], 0, 0, 0);
      }
    __builtin_amdgcn_s_setprio(0);
  }

  // epilogue: |x|^2 only. C/D: col=l&31, row=(reg&3)+8*(reg>>2)+4*(l>>5)
  const int gcol = g0 + wn * 32 + (l & 31);
  const int rbase = wm * 128 + 4 * (l >> 5);
#pragma unroll
  for (int mi = 0; mi < 4; ++mi) {
    const f32x16 r = accr[mi], q = acci[mi];
#pragma unroll
    for (int reg = 0; reg < 16; ++reg) {
      const int row = rbase + mi * 32 + (reg & 3) + 8 * (reg >> 2);
      xabs[(size_t)(b0 + row) * G_DIM + gcol] = r[reg] * r[reg] + q[reg] * q[reg];
    }
  }
}

// ---------- K2b: per-row max + candidate scan + zero-fill (block per row) ----
__global__ __launch_bounds__(256) void k_scan(float* __restrict__ xabs,
                                              int* __restrict__ ccnt,
                                              int* __restrict__ cg) {
  __shared__ float red[4];
  const int b = blockIdx.x, tid = threadIdx.x;
  const int l = tid & 63, w = tid >> 6;
  float4 v[4];
  float m = -1.f;
#pragma unroll
  for (int j = 0; j < 4; ++j) {
    v[j] = *reinterpret_cast<const float4*>(xabs + (size_t)b * G_DIM + j * 1024 + tid * 4);
    m = fmaxf(m, fmaxf(fmaxf(v[j].x, v[j].y), fmaxf(v[j].z, v[j].w)));
  }
#pragma unroll
  for (int off = 32; off; off >>= 1) m = fmaxf(m, __shfl_xor(m, off));
  if (l == 0) red[w] = m;
  __syncthreads();
  const float thr = fmaxf(fmaxf(red[0], red[1]), fmaxf(red[2], red[3])) - 0.25f;
#pragma unroll
  for (int j = 0; j < 4; ++j) {
    const int gb = j * 1024 + tid * 4;
    if (v[j].x >= thr) { int p = atomicAdd(&ccnt[b], 1); if (p < 64) cg[b * 64 + p] = gb; }
    if (v[j].y >= thr) { int p = atomicAdd(&ccnt[b], 1); if (p < 64) cg[b * 64 + p] = gb + 1; }
    if (v[j].z >= thr) { int p = atomicAdd(&ccnt[b], 1); if (p < 64) cg[b * 64 + p] = gb + 2; }
    if (v[j].w >= thr) { int p = atomicAdd(&ccnt[b], 1); if (p < 64) cg[b * 64 + p] = gb + 3; }
    *reinterpret_cast<float4*>(xabs + (size_t)b * G_DIM + gb) = (float4){0.f, 0.f, 0.f, 0.f};
  }
}

// ---------- K3: fp64 refinement of candidates -> winner ----------
__global__ void k_refine(const float* __restrict__ H, const float* __restrict__ prT,
                         const float* __restrict__ piT, const int* __restrict__ ccnt,
                         const int* __restrict__ cg, int* __restrict__ wg,
                         float* __restrict__ wxr, float* __restrict__ wxi) {
  __shared__ double red[8];
  const int b = blockIdx.x, tid = threadIdx.x;
  const int l = tid & 63, w = tid >> 6;
  int cnt = ccnt[b];
  if (cnt > 64) cnt = 64;
  double best = -1.0, bxr = 0.0, bxi = 0.0;
  int bg = 0;
  for (int ci = 0; ci < cnt; ++ci) {
    const int g = cg[b * 64 + ci];
    double xr = 0.0, xi = 0.0;
    for (int n = tid; n < N_DIM; n += 256) {
      const double hr = H[(size_t)b * N_DIM + n];
      const double hi = H[(size_t)B_DIM * N_DIM + (size_t)b * N_DIM + n];
      const double pr = prT[(size_t)g * N_DIM + n];
      const double pi = piT[(size_t)g * N_DIM + n];
      xr += hr * pr - hi * pi;
      xi += hr * pi + hi * pr;
    }
    for (int off = 32; off; off >>= 1) {
      xr += __shfl_down(xr, off);
      xi += __shfl_down(xi, off);
    }
    if (l == 0) { red[w * 2] = xr; red[w * 2 + 1] = xi; }
    __syncthreads();
    if (tid == 0) {
      const double sxr = red[0] + red[2] + red[4] + red[6];
      const double sxi = red[1] + red[3] + red[5] + red[7];
      const double xab = sxr * sxr + sxi * sxi;
      if (xab > best || (xab == best && g < bg)) { best = xab; bg = g; bxr = sxr; bxi = sxi; }
    }
    __syncthreads();
  }
  if (tid == 0) { wg[b] = bg; wxr[b] = (float)bxr; wxi[b] = (float)bxi; }
}

// ---------- K4: y = winner x conj(PSI column) ----------
__global__ void k_y(const float* __restrict__ prT, const float* __restrict__ piT,
                    const int* __restrict__ wg, const float* __restrict__ wxr,
                    const float* __restrict__ wxi, float* __restrict__ out) {
  const int b = blockIdx.x, tid = threadIdx.x;
  const int g = wg[b];
  const float xr = wxr[b], xi = wxi[b];
  float* yr = out + (size_t)2 * B_DIM * G_DIM + (size_t)b * N_DIM;
  float* yi = yr + (size_t)B_DIM * N_DIM;
  for (int n = tid; n < N_DIM; n += 256) {
    const float pr = prT[(size_t)g * N_DIM + n], pi = piT[(size_t)g * N_DIM + n];
    yr[n] = xr * pr + xi * pi;
    yi[n] = xi * pr - xr * pi;
  }
}

// ---------- K5: scatter winner values into zeroed x ----------
__global__ void k_scatter(const int* __restrict__ wg, const float* __restrict__ wxr,
                          const float* __restrict__ wxi, float* __restrict__ out) {
  const int b = blockIdx.x * 256 + threadIdx.x;
  if (b < B_DIM) {
    const int g = wg[b];
    out[(size_t)b * G_DIM + g] = wxr[b];
    out[(size_t)B_DIM * G_DIM + (size_t)b * G_DIM + g] = wxi[b];
  }
}

extern "C" void kernel_launch(void* const* d_in, const int* in_sizes, int n_in,
                              void* d_out, int out_size, void* d_ws, size_t ws_size,
                              hipStream_t stream) {
  const float* H = (const float*)d_in[0];
  const float* theta = (const float*)d_in[1];
  const float* alpha = (const float*)d_in[2];
  float* out = (float*)d_out;
  char* ws = (char*)d_ws;

  ushort_t* brT = (ushort_t*)(ws + WS_BRT);
  ushort_t* biT = (ushort_t*)(ws + WS_BIT);
  ushort_t* hbf = (ushort_t*)(ws + WS_HBF);
  int* ccnt = (int*)(ws + WS_CCNT);
  int* cg = (int*)(ws + WS_CG);
  int* wg = (int*)(ws + WS_WG);
  float* wxr = (float*)(ws + WS_WXR);
  float* wxi = (float*)(ws + WS_WXI);

  // d_out x-region doubles as scratch until the final memset+scatter:
  float* prT = out;                 // [G][N] f32 (x-real plane)
  float* piT = out + 4194304;       // second half of x-real plane
  float* xabs = out + 8388608;      // [B][G] f32 (x-imag plane)

  hipMemsetAsync(ws + WS_CCNT, 0, 8192, stream);  // ccnt

  k_psi<<<dim3(G_DIM / 32, N_DIM / 32), dim3(32, 8), 0, stream>>>(theta, alpha, prT, piT, brT, biT);
  k_hconv<<<4096, 256, 0, stream>>>(H, hbf);
  k_gemm<<<256, 512, 0, stream>>>(hbf, brT, biT, xabs);
  k_scan<<<B_DIM, 256, 0, stream>>>(xabs, ccnt, cg);  // row max + scan + zero imag plane
  k_refine<<<B_DIM, 256, 0, stream>>>(H, prT, piT, ccnt, cg, wg, wxr, wxi);
  k_y<<<B_DIM, 256, 0, stream>>>(prT, piT, wg, wxr, wxi, out);
  hipMemsetAsync(out, 0, (size_t)B_DIM * G_DIM * 4, stream);  // zero real plane (prT/piT scratch)
  k_scatter<<<8, 256, 0, stream>>>(wg, wxr, wxi, out);
}

// Round 8
// 143.724 us; speedup vs baseline: 1.2987x; 1.0104x over previous
//
#include <hip/hip_runtime.h>
#include <math.h>

#define N_DIM 1024
#define G_DIM 4096
#define B_DIM 2048
#define K2DIM 2048  // 2*N (real|imag concatenated K)

typedef __attribute__((ext_vector_type(8))) short bf16x8;
typedef __attribute__((ext_vector_type(8))) unsigned short u16x8;
typedef __attribute__((ext_vector_type(16))) float f32x16;
typedef unsigned short ushort_t;

// ---------- ws layout (bytes) ----------
#define WS_PRBF  0u                      // bf16 [G][1024]   8 MB
#define WS_PIBF  (8u << 20)              // bf16 [G][1024]   8 MB
#define WS_HBF   (16u << 20)             // bf16 [B][2048]   8 MB ([Hr | -Hi])
#define WS_CCNT  (24u << 20)             // int [B]
#define WS_CG    (WS_CCNT + 8192u)       // int [B][64]
#define WS_WG    (WS_CG + 2048u*64u*4u)  // int [B]
#define WS_WXR   (WS_WG + 8192u)         // f32 [B]
#define WS_WXI   (WS_WXR + 8192u)        // f32 [B]

__device__ __forceinline__ unsigned short f2bf(float f) {
  unsigned u = __float_as_uint(f);
  unsigned r = u + 0x7fffu + ((u >> 16) & 1u);
  return (unsigned short)(r >> 16);
}
__device__ __forceinline__ float bf2f(unsigned short u) {
  return __uint_as_float(((unsigned)u) << 16);
}
__device__ __forceinline__ bf16x8 negbf(bf16x8 v) {
  union { bf16x8 b; uint4 u; } x;
  x.b = v;
  x.u.x ^= 0x80008000u; x.u.y ^= 0x80008000u;
  x.u.z ^= 0x80008000u; x.u.w ^= 0x80008000u;
  return x.b;
}

__device__ __forceinline__ void gload_lds16(const void* gsrc, void* ldst) {
  __builtin_amdgcn_global_load_lds(
      (const __attribute__((address_space(1))) void*)gsrc,
      (__attribute__((address_space(3))) void*)ldst, 16, 0, 0);
}

// ---------- K1: PSI generation ----------
__global__ void k_psi(const float* __restrict__ theta, const float* __restrict__ alpha,
                      float* __restrict__ prT, float* __restrict__ piT,
                      ushort_t* __restrict__ prBf, ushort_t* __restrict__ piBf) {
  __shared__ float sp[32][33], si[32][33];
  const int tx = threadIdx.x, ty = threadIdx.y;
  const int g0 = blockIdx.x * 32, n0 = blockIdx.y * 32;
  for (int rr = ty; rr < 32; rr += 8) {
    const size_t idx = (size_t)(n0 + rr) * G_DIM + g0 + tx;
    float a = tanhf(alpha[idx]) * 0.03125f;  // 1/sqrt(1024)
    float s, c;
    sincosf(theta[idx], &s, &c);
    sp[rr][tx] = a * c;
    si[rr][tx] = a * s;
  }
  __syncthreads();
  for (int rr = ty; rr < 32; rr += 8) {
    const int g = g0 + rr, n = n0 + tx;
    const float pr = sp[tx][rr], pi = si[tx][rr];
    prT[(size_t)g * N_DIM + n] = pr;
    piT[(size_t)g * N_DIM + n] = pi;
    prBf[(size_t)g * N_DIM + n] = f2bf(pr);
    piBf[(size_t)g * N_DIM + n] = f2bf(pi);
  }
}

// ---------- K1b: H -> bf16, layout [B][2048] = [Hr | -Hi] ----------
__global__ void k_hconv(const float* __restrict__ H, ushort_t* __restrict__ hbf) {
  const int j4 = (blockIdx.x * blockDim.x + threadIdx.x) * 4;
  const int b = j4 >> 11, k = j4 & 2047, c = k >> 10, n = k & 1023;
  float4 v = *reinterpret_cast<const float4*>(
      H + (size_t)c * (B_DIM * N_DIM) + (size_t)b * N_DIM + n);
  if (c) { v.x = -v.x; v.y = -v.y; v.z = -v.z; v.w = -v.w; }
  ushort4 u;
  u.x = f2bf(v.x); u.y = f2bf(v.y); u.z = f2bf(v.z); u.w = f2bf(v.w);
  *reinterpret_cast<ushort4*>(hbf + j4) = u;
}

#define LGKM(n) asm volatile("s_waitcnt lgkmcnt(" #n ")" ::: "memory")
#define SB0() __builtin_amdgcn_sched_barrier(0)

// ---------- K2: merged-B 32x32x16 dual-acc GEMM -> |x|^2 (bf16) ----------
// BM=256, BN=128, merged tile = 32 k-lo + 32 k-hi (64 concat-K). 8 waves (2Mx4N).
// LDS/tile: A[256][64] 32K (slots 0-3 = k-lo of Hr.., 4-7 = k-hi of -Hi) +
// B[128][64] 16K (slots 0-3 = Pr, 4-7 = Pi) = 48K; dbuf 96K. Swizzle slot^=row&7.
// accr = aL*pr + aH*pi ; acci = aL*pi + aH*(-pr)   (aH = -Hi)
__global__ __launch_bounds__(512, 2) void k_gemm(
    const ushort_t* __restrict__ hbf, const ushort_t* __restrict__ prBf,
    const ushort_t* __restrict__ piBf, ushort_t* __restrict__ xabsBf) {
  __shared__ ushort_t smem[49152];     // 96 KB: 2 bufs x 24576 ushorts
  const int tid = threadIdx.x;
  const int l = tid & 63, w = tid >> 6;
  const int wm = w >> 2, wn = w & 3;
  const int bid = blockIdx.x;
  const int xcd = bid & 7, idx = bid >> 3;
  const int g0 = (xcd * 4 + (idx & 3)) * 128;
  const int b0 = (idx >> 2) * 256;

  // fragment offsets: rows 64 ushorts (128 B), slot ^= row&7 (row&7 == l&7)
  const int h = l >> 5;
  int colL[2], colH[2];
#pragma unroll
  for (int ks = 0; ks < 2; ++ks) {
    colL[ks] = ((ks * 2 + h) ^ (l & 7)) * 8;
    colH[ks] = ((4 + ks * 2 + h) ^ (l & 7)) * 8;
  }
  int rowA[4];
#pragma unroll
  for (int mi = 0; mi < 4; ++mi) rowA[mi] = (wm * 128 + mi * 32 + (l & 31)) * 64;
  const int rowB = 16384 + (wn * 32 + (l & 31)) * 64;

  // staging: linear LDS dest, inverse-swizzled global source
  const int rT = tid >> 3, sd = tid & 7, sl = sd ^ (rT & 7);
  const ushort_t* srcA = hbf + (sl < 4 ? sl * 8 : 1024 + (sl - 4) * 8);
  const ushort_t* srcB = (sl < 4) ? (prBf + sl * 8) : (piBf + (sl - 4) * 8);
  const int dBase = (tid & ~63) * 8;

  f32x16 accr[4], acci[4];
#pragma unroll
  for (int mi = 0; mi < 4; ++mi) {
    accr[mi] = (f32x16)(0.f);
    acci[mi] = (f32x16)(0.f);
  }

  // prologue: stage tile 0 into buf 0
#pragma unroll
  for (int i = 0; i < 4; ++i)
    gload_lds16(srcA + (size_t)(b0 + i * 64 + rT) * K2DIM, (void*)(smem + i * 4096 + dBase));
#pragma unroll
  for (int i = 0; i < 2; ++i)
    gload_lds16(srcB + (size_t)(g0 + i * 64 + rT) * N_DIM, (void*)(smem + 16384 + i * 4096 + dBase));
  asm volatile("s_waitcnt vmcnt(0)" ::: "memory");
  __builtin_amdgcn_s_barrier();

  bf16x8 aA[2][2], aB[2][2], pr[2], pi[2], prN[2];

  // pre-read aA = aL(mi 0-1) of tile 0
  {
    const ushort_t* buf = smem;
#pragma unroll
    for (int mi = 0; mi < 2; ++mi)
#pragma unroll
      for (int ks = 0; ks < 2; ++ks)
        aA[mi][ks] = *(const bf16x8*)&buf[rowA[mi] + colL[ks]];
  }

  for (int t = 0; t < 32; ++t) {
    const ushort_t* buf = smem + (t & 1) * 24576;
    const int nb = ((t + 1) & 1) * 24576;
    const int kp = (t + 1) * 32;
    const bool pf = (t < 31);

    // ---- P0: read pr/pi; read aB=aL(mi 2-3); stage A(0,1); S0
#pragma unroll
    for (int ks = 0; ks < 2; ++ks) {
      pr[ks] = *(const bf16x8*)&buf[rowB + colL[ks]];
      pi[ks] = *(const bf16x8*)&buf[rowB + colH[ks]];
    }
    SB0();
#pragma unroll
    for (int mi = 0; mi < 2; ++mi)
#pragma unroll
      for (int ks = 0; ks < 2; ++ks)
        aB[mi][ks] = *(const bf16x8*)&buf[rowA[mi + 2] + colL[ks]];
    if (pf) {
#pragma unroll
      for (int i = 0; i < 2; ++i)
        gload_lds16(srcA + (size_t)(b0 + i * 64 + rT) * K2DIM + kp,
                    (void*)(smem + nb + i * 4096 + dBase));
    }
    LGKM(4); SB0();
    __builtin_amdgcn_s_setprio(1);
#pragma unroll
    for (int mi = 0; mi < 2; ++mi)
#pragma unroll
      for (int ks = 0; ks < 2; ++ks) {
        accr[mi] = __builtin_amdgcn_mfma_f32_32x32x16_bf16(aA[mi][ks], pr[ks], accr[mi], 0, 0, 0);
        acci[mi] = __builtin_amdgcn_mfma_f32_32x32x16_bf16(aA[mi][ks], pi[ks], acci[mi], 0, 0, 0);
      }
    __builtin_amdgcn_s_setprio(0);

    // ---- P1: read aA<-aH(mi 0-1); prN = -pr; stage A(2,3); S1
#pragma unroll
    for (int mi = 0; mi < 2; ++mi)
#pragma unroll
      for (int ks = 0; ks < 2; ++ks)
        aA[mi][ks] = *(const bf16x8*)&buf[rowA[mi] + colH[ks]];
    if (pf) {
#pragma unroll
      for (int i = 0; i < 2; ++i)
        gload_lds16(srcA + (size_t)(b0 + (i + 2) * 64 + rT) * K2DIM + kp,
                    (void*)(smem + nb + (i + 2) * 4096 + dBase));
    }
#pragma unroll
    for (int ks = 0; ks < 2; ++ks) prN[ks] = negbf(pr[ks]);
    LGKM(4); SB0();
    __builtin_amdgcn_s_setprio(1);
#pragma unroll
    for (int mi = 0; mi < 2; ++mi)
#pragma unroll
      for (int ks = 0; ks < 2; ++ks) {
        accr[mi + 2] = __builtin_amdgcn_mfma_f32_32x32x16_bf16(aB[mi][ks], pr[ks], accr[mi + 2], 0, 0, 0);
        acci[mi + 2] = __builtin_amdgcn_mfma_f32_32x32x16_bf16(aB[mi][ks], pi[ks], acci[mi + 2], 0, 0, 0);
      }
    __builtin_amdgcn_s_setprio(0);

    // ---- P2: read aB<-aH(mi 2-3); stage B(0,1); S2
#pragma unroll
    for (int mi = 0; mi < 2; ++mi)
#pragma unroll
      for (int ks = 0; ks < 2; ++ks)
        aB[mi][ks] = *(const bf16x8*)&buf[rowA[mi + 2] + colH[ks]];
    if (pf) {
#pragma unroll
      for (int i = 0; i < 2; ++i)
        gload_lds16(srcB + (size_t)(g0 + i * 64 + rT) * N_DIM + kp,
                    (void*)(smem + nb + 16384 + i * 4096 + dBase));
    }
    LGKM(4); SB0();
    __builtin_amdgcn_s_setprio(1);
#pragma unroll
    for (int mi = 0; mi < 2; ++mi)
#pragma unroll
      for (int ks = 0; ks < 2; ++ks) {
        accr[mi] = __builtin_amdgcn_mfma_f32_32x32x16_bf16(aA[mi][ks], pi[ks], accr[mi], 0, 0, 0);
        acci[mi] = __builtin_amdgcn_mfma_f32_32x32x16_bf16(aA[mi][ks], prN[ks], acci[mi], 0, 0, 0);
      }
    __builtin_amdgcn_s_setprio(0);

    // ---- P3: tile boundary; pre-read next aL(mi 0-1); S3
    LGKM(0); SB0();
    if (pf) {
      asm volatile("s_waitcnt vmcnt(0)" ::: "memory");
      __builtin_amdgcn_s_barrier();
      const ushort_t* bn = smem + nb;
#pragma unroll
      for (int mi = 0; mi < 2; ++mi)
#pragma unroll
        for (int ks = 0; ks < 2; ++ks)
          aA[mi][ks] = *(const bf16x8*)&bn[rowA[mi] + colL[ks]];
      SB0();
    }
    __builtin_amdgcn_s_setprio(1);
#pragma unroll
    for (int mi = 0; mi < 2; ++mi)
#pragma unroll
      for (int ks = 0; ks < 2; ++ks) {
        accr[mi + 2] = __builtin_amdgcn_mfma_f32_32x32x16_bf16(aB[mi][ks], pi[ks], accr[mi + 2], 0, 0, 0);
        acci[mi + 2] = __builtin_amdgcn_mfma_f32_32x32x16_bf16(aB[mi][ks], prN[ks], acci[mi + 2], 0, 0, 0);
      }
    __builtin_amdgcn_s_setprio(0);
  }

  // epilogue: |x|^2 as bf16. C/D: col=l&31, row=(reg&3)+8*(reg>>2)+4*(l>>5)
  const int gcol = g0 + wn * 32 + (l & 31);
  const int rbase = wm * 128 + 4 * (l >> 5);
#pragma unroll
  for (int mi = 0; mi < 4; ++mi) {
    const f32x16 r = accr[mi], q = acci[mi];
#pragma unroll
    for (int reg = 0; reg < 16; ++reg) {
      const int row = rbase + mi * 32 + (reg & 3) + 8 * (reg >> 2);
      xabsBf[(size_t)(b0 + row) * G_DIM + gcol] = f2bf(r[reg] * r[reg] + q[reg] * q[reg]);
    }
  }
}

// ---------- K2b: row max + candidate scan (bf16 xabs) + zero imag plane ----
__global__ __launch_bounds__(256) void k_scan(const ushort_t* __restrict__ xb,
                                              float* __restrict__ ximag,
                                              int* __restrict__ ccnt,
                                              int* __restrict__ cg) {
  __shared__ float red[4];
  const int b = blockIdx.x, tid = threadIdx.x;
  const int l = tid & 63, w = tid >> 6;
  const ushort_t* row = xb + (size_t)b * G_DIM + tid * 16;
  const u16x8 u0 = *(const u16x8*)row;
  const u16x8 u1 = *(const u16x8*)(row + 8);
  float v[16];
#pragma unroll
  for (int j = 0; j < 8; ++j) { v[j] = bf2f(u0[j]); v[8 + j] = bf2f(u1[j]); }
  float m = v[0];
#pragma unroll
  for (int j = 1; j < 16; ++j) m = fmaxf(m, v[j]);
#pragma unroll
  for (int off = 32; off; off >>= 1) m = fmaxf(m, __shfl_xor(m, off));
  if (l == 0) red[w] = m;
  __syncthreads();
  const float thr = fmaxf(fmaxf(red[0], red[1]), fmaxf(red[2], red[3])) - 0.25f;
#pragma unroll
  for (int j = 0; j < 16; ++j)
    if (v[j] >= thr) { int p = atomicAdd(&ccnt[b], 1); if (p < 64) cg[b * 64 + p] = tid * 16 + j; }
  const float4 z = {0.f, 0.f, 0.f, 0.f};
  float* zr = ximag + (size_t)b * G_DIM + tid * 16;
#pragma unroll
  for (int j = 0; j < 4; ++j) *reinterpret_cast<float4*>(zr + j * 4) = z;
}

// ---------- K3: fp64 refinement of candidates -> winner ----------
__global__ void k_refine(const float* __restrict__ H, const float* __restrict__ prT,
                         const float* __restrict__ piT, const int* __restrict__ ccnt,
                         const int* __restrict__ cg, int* __restrict__ wg,
                         float* __restrict__ wxr, float* __restrict__ wxi) {
  __shared__ double red[8];
  const int b = blockIdx.x, tid = threadIdx.x;
  const int l = tid & 63, w = tid >> 6;
  int cnt = ccnt[b];
  if (cnt > 64) cnt = 64;
  double best = -1.0, bxr = 0.0, bxi = 0.0;
  int bg = 0;
  for (int ci = 0; ci < cnt; ++ci) {
    const int g = cg[b * 64 + ci];
    double xr = 0.0, xi = 0.0;
    for (int n = tid; n < N_DIM; n += 256) {
      const double hr = H[(size_t)b * N_DIM + n];
      const double hi = H[(size_t)B_DIM * N_DIM + (size_t)b * N_DIM + n];
      const double pr = prT[(size_t)g * N_DIM + n];
      const double pi = piT[(size_t)g * N_DIM + n];
      xr += hr * pr - hi * pi;
      xi += hr * pi + hi * pr;
    }
    for (int off = 32; off; off >>= 1) {
      xr += __shfl_down(xr, off);
      xi += __shfl_down(xi, off);
    }
    if (l == 0) { red[w * 2] = xr; red[w * 2 + 1] = xi; }
    __syncthreads();
    if (tid == 0) {
      const double sxr = red[0] + red[2] + red[4] + red[6];
      const double sxi = red[1] + red[3] + red[5] + red[7];
      const double xab = sxr * sxr + sxi * sxi;
      if (xab > best || (xab == best && g < bg)) { best = xab; bg = g; bxr = sxr; bxi = sxi; }
    }
    __syncthreads();
  }
  if (tid == 0) { wg[b] = bg; wxr[b] = (float)bxr; wxi[b] = (float)bxi; }
}

// ---------- K4: y = winner x conj(PSI col, bf16) + zero real-plane chunk ----
__global__ void k_y(const ushort_t* __restrict__ prBf, const ushort_t* __restrict__ piBf,
                    const int* __restrict__ wg, const float* __restrict__ wxr,
                    const float* __restrict__ wxi, float* __restrict__ out) {
  const int b = blockIdx.x, tid = threadIdx.x;
  const int g = wg[b];
  const float xr = wxr[b], xi = wxi[b];
  float* yr = out + (size_t)2 * B_DIM * G_DIM + (size_t)b * N_DIM;
  float* yi = yr + (size_t)B_DIM * N_DIM;
  const int n0 = tid * 4;
  const ushort4 p4 = *reinterpret_cast<const ushort4*>(prBf + (size_t)g * N_DIM + n0);
  const ushort4 q4 = *reinterpret_cast<const ushort4*>(piBf + (size_t)g * N_DIM + n0);
  float4 vr, vi;
  {
    const float pr = bf2f(p4.x), pi = bf2f(q4.x);
    vr.x = xr * pr + xi * pi; vi.x = xi * pr - xr * pi;
  }
  {
    const float pr = bf2f(p4.y), pi = bf2f(q4.y);
    vr.y = xr * pr + xi * pi; vi.y = xi * pr - xr * pi;
  }
  {
    const float pr = bf2f(p4.z), pi = bf2f(q4.z);
    vr.z = xr * pr + xi * pi; vi.z = xi * pr - xr * pi;
  }
  {
    const float pr = bf2f(p4.w), pi = bf2f(q4.w);
    vr.w = xr * pr + xi * pi; vi.w = xi * pr - xr * pi;
  }
  *reinterpret_cast<float4*>(yr + n0) = vr;
  *reinterpret_cast<float4*>(yi + n0) = vi;
  // zero real x-plane chunk b (prT/piT scratch already consumed by k_refine)
  const float4 z = {0.f, 0.f, 0.f, 0.f};
  float* zr = out + (size_t)b * G_DIM + tid * 16;
#pragma unroll
  for (int j = 0; j < 4; ++j) *reinterpret_cast<float4*>(zr + j * 4) = z;
}

// ---------- K5: scatter winner values into zeroed x ----------
__global__ void k_scatter(const int* __restrict__ wg, const float* __restrict__ wxr,
                          const float* __restrict__ wxi, float* __restrict__ out) {
  const int b = blockIdx.x * 256 + threadIdx.x;
  if (b < B_DIM) {
    const int g = wg[b];
    out[(size_t)b * G_DIM + g] = wxr[b];
    out[(size_t)B_DIM * G_DIM + (size_t)b * G_DIM + g] = wxi[b];
  }
}

extern "C" void kernel_launch(void* const* d_in, const int* in_sizes, int n_in,
                              void* d_out, int out_size, void* d_ws, size_t ws_size,
                              hipStream_t stream) {
  const float* H = (const float*)d_in[0];
  const float* theta = (const float*)d_in[1];
  const float* alpha = (const float*)d_in[2];
  float* out = (float*)d_out;
  char* ws = (char*)d_ws;

  ushort_t* prBf = (ushort_t*)(ws + WS_PRBF);
  ushort_t* piBf = (ushort_t*)(ws + WS_PIBF);
  ushort_t* hbf = (ushort_t*)(ws + WS_HBF);
  int* ccnt = (int*)(ws + WS_CCNT);
  int* cg = (int*)(ws + WS_CG);
  int* wg = (int*)(ws + WS_WG);
  float* wxr = (float*)(ws + WS_WXR);
  float* wxi = (float*)(ws + WS_WXI);

  // d_out scratch: real x-plane holds prT/piT; y-region holds bf16 xabs
  float* prT = out;                          // [G][N] f32 (16 MB)
  float* piT = out + 4194304;                // [G][N] f32 (16 MB)
  float* ximag = out + 8388608;              // imag x-plane (32 MB)
  ushort_t* xabsBf = (ushort_t*)(out + 16777216);  // y-region scratch (16 MB)

  hipMemsetAsync(ws + WS_CCNT, 0, 8192, stream);  // ccnt

  k_psi<<<dim3(G_DIM / 32, N_DIM / 32), dim3(32, 8), 0, stream>>>(theta, alpha, prT, piT, prBf, piBf);
  k_hconv<<<4096, 256, 0, stream>>>(H, hbf);
  k_gemm<<<256, 512, 0, stream>>>(hbf, prBf, piBf, xabsBf);
  k_scan<<<B_DIM, 256, 0, stream>>>(xabsBf, ximag, ccnt, cg);
  k_refine<<<B_DIM, 256, 0, stream>>>(H, prT, piT, ccnt, cg, wg, wxr, wxi);
  k_y<<<B_DIM, 256, 0, stream>>>(prBf, piBf, wg, wxr, wxi, out);  // y + zero real plane
  k_scatter<<<8, 256, 0, stream>>>(wg, wxr, wxi, out);
}

// Round 9
// 134.412 us; speedup vs baseline: 1.3887x; 1.0693x over previous
//
#include <hip/hip_runtime.h>
#include <math.h>

#define N_DIM 1024
#define G_DIM 4096
#define B_DIM 2048
#define K2DIM 2048  // 2*N (real|imag concatenated K)

typedef __attribute__((ext_vector_type(8))) short bf16x8;
typedef __attribute__((ext_vector_type(8))) unsigned short u16x8;
typedef __attribute__((ext_vector_type(16))) float f32x16;
typedef unsigned short ushort_t;

// ---------- ws layout (bytes) ----------
#define WS_PRBF  0u                      // bf16 [G][1024]   8 MB
#define WS_PIBF  (8u << 20)              // bf16 [G][1024]   8 MB
#define WS_HBF   (16u << 20)             // bf16 [B][2048]   8 MB ([Hr | -Hi])
#define WS_CCNT  (24u << 20)             // int [B]
#define WS_CG    (WS_CCNT + 8192u)       // int [B][64]
#define WS_WG    (WS_CG + 2048u*64u*4u)  // int [B]
#define WS_WXR   (WS_WG + 8192u)         // f32 [B]
#define WS_WXI   (WS_WXR + 8192u)        // f32 [B]

__device__ __forceinline__ unsigned short f2bf(float f) {
  unsigned u = __float_as_uint(f);
  unsigned r = u + 0x7fffu + ((u >> 16) & 1u);
  return (unsigned short)(r >> 16);
}
__device__ __forceinline__ float bf2f(unsigned short u) {
  return __uint_as_float(((unsigned)u) << 16);
}
__device__ __forceinline__ bf16x8 negbf(bf16x8 v) {
  union { bf16x8 b; uint4 u; } x;
  x.b = v;
  x.u.x ^= 0x80008000u; x.u.y ^= 0x80008000u;
  x.u.z ^= 0x80008000u; x.u.w ^= 0x80008000u;
  return x.b;
}

__device__ __forceinline__ void gload_lds16(const void* gsrc, void* ldst) {
  __builtin_amdgcn_global_load_lds(
      (const __attribute__((address_space(1))) void*)gsrc,
      (__attribute__((address_space(3))) void*)ldst, 16, 0, 0);
}

// ---------- K1: fused PSI generation + H conversion + ccnt zero ----------
__global__ __launch_bounds__(256) void k_prep(
    const float* __restrict__ theta, const float* __restrict__ alpha,
    const float* __restrict__ H,
    float* __restrict__ prT, float* __restrict__ piT,
    ushort_t* __restrict__ prBf, ushort_t* __restrict__ piBf,
    ushort_t* __restrict__ hbf, int* __restrict__ ccnt) {
  __shared__ float sp[32][33], si[32][33];
  const int bid = blockIdx.x, tid = threadIdx.x;
  if (bid < 4096) {
    // PSI part: transpose [N][G] -> [G][N], write f32 + bf16
    const int tx = tid & 31, ty = tid >> 5;
    const int g0 = (bid & 127) * 32, n0 = (bid >> 7) * 32;
    for (int rr = ty; rr < 32; rr += 8) {
      const size_t idx = (size_t)(n0 + rr) * G_DIM + g0 + tx;
      float a = tanhf(alpha[idx]) * 0.03125f;  // 1/sqrt(1024)
      float s, c;
      sincosf(theta[idx], &s, &c);
      sp[rr][tx] = a * c;
      si[rr][tx] = a * s;
    }
    __syncthreads();
    for (int rr = ty; rr < 32; rr += 8) {
      const int g = g0 + rr, n = n0 + tx;
      const float pr = sp[tx][rr], pi = si[tx][rr];
      prT[(size_t)g * N_DIM + n] = pr;
      piT[(size_t)g * N_DIM + n] = pi;
      prBf[(size_t)g * N_DIM + n] = f2bf(pr);
      piBf[(size_t)g * N_DIM + n] = f2bf(pi);
    }
  } else {
    if (bid == 4096) {
      ((int4*)ccnt)[tid] = make_int4(0, 0, 0, 0);
      ((int4*)ccnt)[tid + 256] = make_int4(0, 0, 0, 0);
    }
    // H -> bf16, layout [B][2048] = [Hr | -Hi]
    const int j4 = ((bid - 4096) * 256 + tid) * 4;
    const int b = j4 >> 11, k = j4 & 2047, c = k >> 10, n = k & 1023;
    float4 v = *reinterpret_cast<const float4*>(
        H + (size_t)c * (B_DIM * N_DIM) + (size_t)b * N_DIM + n);
    if (c) { v.x = -v.x; v.y = -v.y; v.z = -v.z; v.w = -v.w; }
    ushort4 u;
    u.x = f2bf(v.x); u.y = f2bf(v.y); u.z = f2bf(v.z); u.w = f2bf(v.w);
    *reinterpret_cast<ushort4*>(hbf + j4) = u;
  }
}

#define LGKM(n) asm volatile("s_waitcnt lgkmcnt(" #n ")" ::: "memory")
#define SB0() __builtin_amdgcn_sched_barrier(0)

// ---------- K2: merged-B 32x32x16 dual-acc GEMM -> |x|^2 (bf16) ----------
// BM=256, BN=128, merged tile = 32 k-lo + 32 k-hi. 8 waves as 4M x 2N
// (per-wave 64x64 out, 16 frag-reads/iter vs 20 of 2Mx4N).
// LDS/tile: A[256][64] 32K + B[128][64] 16K = 48K; dbuf 96K. slot ^= row&7.
// accr = aL*pr + aH*pi ; acci = aL*pi + aH*(-pr)   (aH = -Hi)
__global__ __launch_bounds__(512, 2) void k_gemm(
    const ushort_t* __restrict__ hbf, const ushort_t* __restrict__ prBf,
    const ushort_t* __restrict__ piBf, ushort_t* __restrict__ xabsBf) {
  __shared__ ushort_t smem[49152];     // 96 KB: 2 bufs x 24576 ushorts
  const int tid = threadIdx.x;
  const int l = tid & 63, w = tid >> 6;
  const int wm = w >> 1, wn = w & 1;   // 4M x 2N
  const int bid = blockIdx.x;
  const int xcd = bid & 7, idx = bid >> 3;
  const int g0 = (xcd * 4 + (idx & 3)) * 128;
  const int b0 = (idx >> 2) * 256;

  // fragment offsets: rows 64 ushorts (128 B), slot ^= row&7 (row&7 == l&7)
  const int h = l >> 5;
  int colL[2], colH[2];
#pragma unroll
  for (int ks = 0; ks < 2; ++ks) {
    colL[ks] = ((ks * 2 + h) ^ (l & 7)) * 8;
    colH[ks] = ((4 + ks * 2 + h) ^ (l & 7)) * 8;
  }
  int rowA[2], rowB[2];
#pragma unroll
  for (int mi = 0; mi < 2; ++mi) rowA[mi] = (wm * 64 + mi * 32 + (l & 31)) * 64;
#pragma unroll
  for (int ni = 0; ni < 2; ++ni) rowB[ni] = 16384 + (wn * 64 + ni * 32 + (l & 31)) * 64;

  // staging: linear LDS dest, inverse-swizzled global source
  const int rT = tid >> 3, sd = tid & 7, sl = sd ^ (rT & 7);
  const ushort_t* srcA = hbf + (sl < 4 ? sl * 8 : 1024 + (sl - 4) * 8);
  const ushort_t* srcB = (sl < 4) ? (prBf + sl * 8) : (piBf + (sl - 4) * 8);
  const int dBase = (tid & ~63) * 8;

  f32x16 accr[2][2], acci[2][2];
#pragma unroll
  for (int mi = 0; mi < 2; ++mi)
#pragma unroll
    for (int ni = 0; ni < 2; ++ni) {
      accr[mi][ni] = (f32x16)(0.f);
      acci[mi][ni] = (f32x16)(0.f);
    }

  // prologue: stage tile 0 into buf 0
#pragma unroll
  for (int i = 0; i < 4; ++i)
    gload_lds16(srcA + (size_t)(b0 + i * 64 + rT) * K2DIM, (void*)(smem + i * 4096 + dBase));
#pragma unroll
  for (int i = 0; i < 2; ++i)
    gload_lds16(srcB + (size_t)(g0 + i * 64 + rT) * N_DIM, (void*)(smem + 16384 + i * 4096 + dBase));
  asm volatile("s_waitcnt vmcnt(0)" ::: "memory");
  __builtin_amdgcn_s_barrier();

  bf16x8 aL[2][2], aH[2][2], prB[2][2], piB[2][2], prN[2][2];

  // pre-read aL + prB of tile 0 (8 reads outstanding entering the loop)
  {
    const ushort_t* buf = smem;
#pragma unroll
    for (int mi = 0; mi < 2; ++mi)
#pragma unroll
      for (int ks = 0; ks < 2; ++ks)
        aL[mi][ks] = *(const bf16x8*)&buf[rowA[mi] + colL[ks]];
#pragma unroll
    for (int ni = 0; ni < 2; ++ni)
#pragma unroll
      for (int ks = 0; ks < 2; ++ks)
        prB[ni][ks] = *(const bf16x8*)&buf[rowB[ni] + colL[ks]];
  }

  for (int t = 0; t < 32; ++t) {
    const ushort_t* buf = smem + (t & 1) * 24576;
    const int nb = ((t + 1) & 1) * 24576;
    const int kp = (t + 1) * 32;
    const bool pf = (t < 31);

    // ---- P0: read piB; stage A(0,1); S0: accr += aL*pr
#pragma unroll
    for (int ni = 0; ni < 2; ++ni)
#pragma unroll
      for (int ks = 0; ks < 2; ++ks)
        piB[ni][ks] = *(const bf16x8*)&buf[rowB[ni] + colH[ks]];
    if (pf) {
#pragma unroll
      for (int i = 0; i < 2; ++i)
        gload_lds16(srcA + (size_t)(b0 + i * 64 + rT) * K2DIM + kp,
                    (void*)(smem + nb + i * 4096 + dBase));
    }
    LGKM(4); SB0();
    __builtin_amdgcn_s_setprio(1);
#pragma unroll
    for (int mi = 0; mi < 2; ++mi)
#pragma unroll
      for (int ni = 0; ni < 2; ++ni)
#pragma unroll
        for (int ks = 0; ks < 2; ++ks)
          accr[mi][ni] = __builtin_amdgcn_mfma_f32_32x32x16_bf16(aL[mi][ks], prB[ni][ks], accr[mi][ni], 0, 0, 0);
    __builtin_amdgcn_s_setprio(0);

    // ---- P1: read aH; stage A(2,3) + B(0,1); S1: acci += aL*pi
#pragma unroll
    for (int mi = 0; mi < 2; ++mi)
#pragma unroll
      for (int ks = 0; ks < 2; ++ks)
        aH[mi][ks] = *(const bf16x8*)&buf[rowA[mi] + colH[ks]];
    if (pf) {
#pragma unroll
      for (int i = 0; i < 2; ++i)
        gload_lds16(srcA + (size_t)(b0 + (i + 2) * 64 + rT) * K2DIM + kp,
                    (void*)(smem + nb + (i + 2) * 4096 + dBase));
#pragma unroll
      for (int i = 0; i < 2; ++i)
        gload_lds16(srcB + (size_t)(g0 + i * 64 + rT) * N_DIM + kp,
                    (void*)(smem + nb + 16384 + i * 4096 + dBase));
    }
    LGKM(4); SB0();
    __builtin_amdgcn_s_setprio(1);
#pragma unroll
    for (int mi = 0; mi < 2; ++mi)
#pragma unroll
      for (int ni = 0; ni < 2; ++ni)
#pragma unroll
        for (int ks = 0; ks < 2; ++ks)
          acci[mi][ni] = __builtin_amdgcn_mfma_f32_32x32x16_bf16(aL[mi][ks], piB[ni][ks], acci[mi][ni], 0, 0, 0);
    __builtin_amdgcn_s_setprio(0);

    // ---- P2: prN = -prB; S2: accr += aH*pi
#pragma unroll
    for (int ni = 0; ni < 2; ++ni)
#pragma unroll
      for (int ks = 0; ks < 2; ++ks)
        prN[ni][ks] = negbf(prB[ni][ks]);
    LGKM(0); SB0();
    __builtin_amdgcn_s_setprio(1);
#pragma unroll
    for (int mi = 0; mi < 2; ++mi)
#pragma unroll
      for (int ni = 0; ni < 2; ++ni)
#pragma unroll
        for (int ks = 0; ks < 2; ++ks)
          accr[mi][ni] = __builtin_amdgcn_mfma_f32_32x32x16_bf16(aH[mi][ks], piB[ni][ks], accr[mi][ni], 0, 0, 0);
    __builtin_amdgcn_s_setprio(0);

    // ---- P3: tile boundary; pre-read next aL+prB; S3: acci += aH*(-pr)
    if (pf) {
      asm volatile("s_waitcnt vmcnt(0)" ::: "memory");
      __builtin_amdgcn_s_barrier();
      const ushort_t* bn = smem + nb;
#pragma unroll
      for (int mi = 0; mi < 2; ++mi)
#pragma unroll
        for (int ks = 0; ks < 2; ++ks)
          aL[mi][ks] = *(const bf16x8*)&bn[rowA[mi] + colL[ks]];
#pragma unroll
      for (int ni = 0; ni < 2; ++ni)
#pragma unroll
        for (int ks = 0; ks < 2; ++ks)
          prB[ni][ks] = *(const bf16x8*)&bn[rowB[ni] + colL[ks]];
      SB0();
    }
    __builtin_amdgcn_s_setprio(1);
#pragma unroll
    for (int mi = 0; mi < 2; ++mi)
#pragma unroll
      for (int ni = 0; ni < 2; ++ni)
#pragma unroll
        for (int ks = 0; ks < 2; ++ks)
          acci[mi][ni] = __builtin_amdgcn_mfma_f32_32x32x16_bf16(aH[mi][ks], prN[ni][ks], acci[mi][ni], 0, 0, 0);
    __builtin_amdgcn_s_setprio(0);
  }

  // epilogue: |x|^2 as bf16. C/D: col=l&31, row=(reg&3)+8*(reg>>2)+4*(l>>5)
  const int rb0 = wm * 64 + 4 * (l >> 5);
#pragma unroll
  for (int mi = 0; mi < 2; ++mi)
#pragma unroll
    for (int ni = 0; ni < 2; ++ni) {
      const int gcol = g0 + wn * 64 + ni * 32 + (l & 31);
      const f32x16 r = accr[mi][ni], q = acci[mi][ni];
#pragma unroll
      for (int reg = 0; reg < 16; ++reg) {
        const int row = rb0 + mi * 32 + (reg & 3) + 8 * (reg >> 2);
        xabsBf[(size_t)(b0 + row) * G_DIM + gcol] = f2bf(r[reg] * r[reg] + q[reg] * q[reg]);
      }
    }
}

// ---------- K2b: row max + candidate scan (bf16 xabs) + zero imag plane ----
__global__ __launch_bounds__(256) void k_scan(const ushort_t* __restrict__ xb,
                                              float* __restrict__ ximag,
                                              int* __restrict__ ccnt,
                                              int* __restrict__ cg) {
  __shared__ float red[4];
  const int b = blockIdx.x, tid = threadIdx.x;
  const int l = tid & 63, w = tid >> 6;
  const ushort_t* row = xb + (size_t)b * G_DIM + tid * 16;
  const u16x8 u0 = *(const u16x8*)row;
  const u16x8 u1 = *(const u16x8*)(row + 8);
  float v[16];
#pragma unroll
  for (int j = 0; j < 8; ++j) { v[j] = bf2f(u0[j]); v[8 + j] = bf2f(u1[j]); }
  float m = v[0];
#pragma unroll
  for (int j = 1; j < 16; ++j) m = fmaxf(m, v[j]);
#pragma unroll
  for (int off = 32; off; off >>= 1) m = fmaxf(m, __shfl_xor(m, off));
  if (l == 0) red[w] = m;
  __syncthreads();
  const float thr = fmaxf(fmaxf(red[0], red[1]), fmaxf(red[2], red[3])) - 0.25f;
#pragma unroll
  for (int j = 0; j < 16; ++j)
    if (v[j] >= thr) { int p = atomicAdd(&ccnt[b], 1); if (p < 64) cg[b * 64 + p] = tid * 16 + j; }
  const float4 z = {0.f, 0.f, 0.f, 0.f};
  float* zr = ximag + (size_t)b * G_DIM + tid * 16;
#pragma unroll
  for (int j = 0; j < 4; ++j) *reinterpret_cast<float4*>(zr + j * 4) = z;
}

// ---------- K3: fp64 refinement of candidates -> winner ----------
__global__ void k_refine(const float* __restrict__ H, const float* __restrict__ prT,
                         const float* __restrict__ piT, const int* __restrict__ ccnt,
                         const int* __restrict__ cg, int* __restrict__ wg,
                         float* __restrict__ wxr, float* __restrict__ wxi) {
  __shared__ double red[8];
  const int b = blockIdx.x, tid = threadIdx.x;
  const int l = tid & 63, w = tid >> 6;
  int cnt = ccnt[b];
  if (cnt > 64) cnt = 64;
  double best = -1.0, bxr = 0.0, bxi = 0.0;
  int bg = 0;
  for (int ci = 0; ci < cnt; ++ci) {
    const int g = cg[b * 64 + ci];
    double xr = 0.0, xi = 0.0;
    for (int n = tid; n < N_DIM; n += 256) {
      const double hr = H[(size_t)b * N_DIM + n];
      const double hi = H[(size_t)B_DIM * N_DIM + (size_t)b * N_DIM + n];
      const double pr = prT[(size_t)g * N_DIM + n];
      const double pi = piT[(size_t)g * N_DIM + n];
      xr += hr * pr - hi * pi;
      xi += hr * pi + hi * pr;
    }
    for (int off = 32; off; off >>= 1) {
      xr += __shfl_down(xr, off);
      xi += __shfl_down(xi, off);
    }
    if (l == 0) { red[w * 2] = xr; red[w * 2 + 1] = xi; }
    __syncthreads();
    if (tid == 0) {
      const double sxr = red[0] + red[2] + red[4] + red[6];
      const double sxi = red[1] + red[3] + red[5] + red[7];
      const double xab = sxr * sxr + sxi * sxi;
      if (xab > best || (xab == best && g < bg)) { best = xab; bg = g; bxr = sxr; bxi = sxi; }
    }
    __syncthreads();
  }
  if (tid == 0) { wg[b] = bg; wxr[b] = (float)bxr; wxi[b] = (float)bxi; }
}

// ---------- K4: y = winner x conj(PSI col) + zero real chunk + scatter x ----
__global__ void k_y(const ushort_t* __restrict__ prBf, const ushort_t* __restrict__ piBf,
                    const int* __restrict__ wg, const float* __restrict__ wxr,
                    const float* __restrict__ wxi, float* __restrict__ out) {
  const int b = blockIdx.x, tid = threadIdx.x;
  const int g = wg[b];
  const float xr = wxr[b], xi = wxi[b];
  float* yr = out + (size_t)2 * B_DIM * G_DIM + (size_t)b * N_DIM;
  float* yi = yr + (size_t)B_DIM * N_DIM;
  const int n0 = tid * 4;
  const ushort4 p4 = *reinterpret_cast<const ushort4*>(prBf + (size_t)g * N_DIM + n0);
  const ushort4 q4 = *reinterpret_cast<const ushort4*>(piBf + (size_t)g * N_DIM + n0);
  float4 vr, vi;
  { const float pr = bf2f(p4.x), pi = bf2f(q4.x); vr.x = xr * pr + xi * pi; vi.x = xi * pr - xr * pi; }
  { const float pr = bf2f(p4.y), pi = bf2f(q4.y); vr.y = xr * pr + xi * pi; vi.y = xi * pr - xr * pi; }
  { const float pr = bf2f(p4.z), pi = bf2f(q4.z); vr.z = xr * pr + xi * pi; vi.z = xi * pr - xr * pi; }
  { const float pr = bf2f(p4.w), pi = bf2f(q4.w); vr.w = xr * pr + xi * pi; vi.w = xi * pr - xr * pi; }
  *reinterpret_cast<float4*>(yr + n0) = vr;
  *reinterpret_cast<float4*>(yi + n0) = vi;
  // zero real x-plane row b (prT/piT scratch already consumed by k_refine)
  const float4 z = {0.f, 0.f, 0.f, 0.f};
  float* zr = out + (size_t)b * G_DIM + tid * 16;
#pragma unroll
  for (int j = 0; j < 4; ++j) *reinterpret_cast<float4*>(zr + j * 4) = z;
  __syncthreads();
  if (tid == 0) {
    out[(size_t)b * G_DIM + g] = xr;                           // x real
    out[(size_t)B_DIM * G_DIM + (size_t)b * G_DIM + g] = xi;   // x imag
  }
}

extern "C" void kernel_launch(void* const* d_in, const int* in_sizes, int n_in,
                              void* d_out, int out_size, void* d_ws, size_t ws_size,
                              hipStream_t stream) {
  const float* H = (const float*)d_in[0];
  const float* theta = (const float*)d_in[1];
  const float* alpha = (const float*)d_in[2];
  float* out = (float*)d_out;
  char* ws = (char*)d_ws;

  ushort_t* prBf = (ushort_t*)(ws + WS_PRBF);
  ushort_t* piBf = (ushort_t*)(ws + WS_PIBF);
  ushort_t* hbf = (ushort_t*)(ws + WS_HBF);
  int* ccnt = (int*)(ws + WS_CCNT);
  int* cg = (int*)(ws + WS_CG);
  int* wg = (int*)(ws + WS_WG);
  float* wxr = (float*)(ws + WS_WXR);
  float* wxi = (float*)(ws + WS_WXI);

  // d_out scratch: real x-plane holds prT/piT; y-region holds bf16 xabs
  float* prT = out;                          // [G][N] f32 (16 MB)
  float* piT = out + 4194304;                // [G][N] f32 (16 MB)
  float* ximag = out + 8388608;              // imag x-plane (32 MB)
  ushort_t* xabsBf = (ushort_t*)(out + 16777216);  // y-region scratch (16 MB)

  k_prep<<<8192, 256, 0, stream>>>(theta, alpha, H, prT, piT, prBf, piBf, hbf, ccnt);
  k_gemm<<<256, 512, 0, stream>>>(hbf, prBf, piBf, xabsBf);
  k_scan<<<B_DIM, 256, 0, stream>>>(xabsBf, ximag, ccnt, cg);
  k_refine<<<B_DIM, 256, 0, stream>>>(H, prT, piT, ccnt, cg, wg, wxr, wxi);
  k_y<<<B_DIM, 256, 0, stream>>>(prBf, piBf, wg, wxr, wxi, out);  // y + zero + scatter
}